// Round 3
// baseline (4440.533 us; speedup 1.0000x reference)
//
#include <hip/hip_runtime.h>

typedef unsigned short u16;
typedef unsigned int u32;
typedef __attribute__((ext_vector_type(8))) short short8;
typedef __attribute__((ext_vector_type(4))) float f32x4;

#define HD 128

__device__ inline float b2f(u16 u){ u32 v = ((u32)u) << 16; return __uint_as_float(v); }
__device__ inline u16 f2b(float f){
  u32 u = __float_as_uint(f);
  u32 r = (u + 0x7fffu + ((u >> 16) & 1u)) >> 16;
  return (u16)r;
}
__device__ inline float eluf(float x){ return x > 0.f ? x : __expf(x) - 1.f; }
__device__ inline float reluf(float x){ return x > 0.f ? x : 0.f; }
__device__ inline float sane(float x){
  if (!(x == x)) return 0.f;
  return fminf(fmaxf(x, -1e30f), 1e30f);
}

// ---------------- small precompute: softmaxes, 1+eps, ws/wd = gat_W^T @ a ----
__global__ void k_small(const float* __restrict__ na_a, const float* __restrict__ sc_a,
                        const float* __restrict__ la_a, const float* __restrict__ gatW,
                        const float* __restrict__ gat_as, const float* __restrict__ gat_ad,
                        const float* __restrict__ gin_eps, float* __restrict__ sm)
{
  int t = threadIdx.x;
  if (t == 0){
    for (int l = 0; l < 3; l++){
      float a[4]; float mx = -1e30f;
      for (int i = 0; i < 4; i++){ a[i] = na_a[l*4+i]; mx = fmaxf(mx, a[i]); }
      float ssum = 0.f;
      for (int i = 0; i < 4; i++){ a[i] = __expf(a[i]-mx); ssum += a[i]; }
      for (int i = 0; i < 4; i++) sm[l*4+i] = a[i]/ssum;
    }
    for (int r = 0; r < 2; r++){
      float a0 = sc_a[r*2], a1 = sc_a[r*2+1];
      float mx = fmaxf(a0,a1);
      float e0 = __expf(a0-mx), e1 = __expf(a1-mx);
      sm[12+r] = e1/(e0+e1);
    }
    {
      float a0=la_a[0], a1=la_a[1], a2=la_a[2];
      float mx = fmaxf(fmaxf(a0,a1),a2);
      float e0=__expf(a0-mx), e1=__expf(a1-mx), e2=__expf(a2-mx);
      float ssum = e0+e1+e2;
      sm[14]=e0/ssum; sm[15]=e1/ssum; sm[16]=e2/ssum;
    }
    for (int l=0;l<3;l++) sm[17+l] = 1.f + gin_eps[l];
  }
  if (t < 128){
    for (int l=0;l<3;l++){
      float a1=0.f, a2=0.f;
      for (int k=0;k<128;k++){
        float wv = gatW[l*16384 + k*128 + t];
        a1 = fmaf(wv, gat_as[l*128+k], a1);
        a2 = fmaf(wv, gat_ad[l*128+k], a2);
      }
      sm[32  + l*128 + t] = a1;
      sm[416 + l*128 + t] = a2;
    }
  }
}

// ---------------- CSR build ----------------
__global__ void k_count(const int* __restrict__ ei, int E, int* __restrict__ cnt){
  int e = blockIdx.x*256 + threadIdx.x;
  if (e < E) atomicAdd(&cnt[ei[E + e]], 1);
}

__global__ void k_scan(const int* __restrict__ cnt, int* __restrict__ rowptr,
                       int* __restrict__ cursor, int Nn)
{
  __shared__ int part[1024];
  int t = threadIdx.x;
  int chunk = (Nn + 1023) >> 10;
  int base = t*chunk;
  int lim = min(base + chunk, Nn);
  int s = 0;
  for (int i = base; i < lim; i++) s += cnt[i];
  part[t] = s;
  __syncthreads();
  for (int off = 1; off < 1024; off <<= 1){
    int add = (t >= off) ? part[t - off] : 0;
    __syncthreads();
    part[t] += add;
    __syncthreads();
  }
  int run = part[t] - s;
  for (int i = base; i < lim; i++){
    rowptr[i] = run; cursor[i] = run; run += cnt[i];
  }
  if (t == 1023) rowptr[Nn] = part[1023];
}

__global__ void k_nodeinit(const int* __restrict__ cnt, int Nn,
                           float* __restrict__ dis, float* __restrict__ dinv){
  int v = blockIdx.x*256 + threadIdx.x;
  if (v < Nn){
    int c = cnt[v];
    float f = (float)c;
    dis[v]  = c > 0 ? 1.f/sqrtf(f) : 0.f;
    dinv[v] = 1.f/fmaxf(f, 1.f);
  }
}

__global__ void k_fill(const int* __restrict__ ei, int E,
                       int* __restrict__ cursor, int* __restrict__ csr){
  int e = blockIdx.x*256 + threadIdx.x;
  if (e < E){
    int sv = ei[e], dv = ei[E + e];
    int pos = atomicAdd(&cursor[dv], 1);
    csr[pos] = sv;
  }
}

// ---------------- per-node GAT scalars: s = x.ws, d = x.wd (X is bf16) ------
__global__ __launch_bounds__(256)
void k_sd(const u16* __restrict__ X, const float* __restrict__ sm, int layer, int Nn,
          float* __restrict__ sout, float* __restrict__ dout)
{
  int wv = blockIdx.x*4 + (threadIdx.x >> 6);
  if (wv >= Nn) return;
  int lane = threadIdx.x & 63;
  u32 xv = *(const u32*)(X + (size_t)wv*HD + lane*2);
  float x0 = b2f((u16)(xv & 0xffff)), x1 = b2f((u16)(xv >> 16));
  const float* wsv = sm + 32  + layer*128;
  const float* wdv = sm + 416 + layer*128;
  float ps = x0*wsv[2*lane] + x1*wsv[2*lane+1];
  float pd = x0*wdv[2*lane] + x1*wdv[2*lane+1];
  #pragma unroll
  for (int off = 32; off > 0; off >>= 1){
    ps += __shfl_xor(ps, off);
    pd += __shfl_xor(pd, off);
  }
  if (lane == 0){ sout[wv] = ps; dout[wv] = pd; }
}

// ---------------- MFMA GEMM helpers (XOR-swizzled LDS, 16x16x32 bf16) -------
// bf16 source (intermediate feature buffers)
__device__ __forceinline__ void stageA(u16* lds, const u16* __restrict__ src,
                                       int mbase, int Nn, int tid){
  #pragma unroll
  for (int i = 0; i < 8; i++){
    int chunk = tid + 256*i;
    int r = chunk >> 4;
    int c = chunk & 15;
    uint4 v = {0u,0u,0u,0u};
    int gr = mbase + r;
    if (gr < Nn) v = *(const uint4*)(src + (size_t)gr*HD + c*8);
    *(uint4*)(lds + (r*16 + (c ^ (r & 15)))*8) = v;
  }
}
// f32 source -> bf16 LDS (8 floats = two float4 per 16B bf16 chunk)
__device__ __forceinline__ uint4 cvt8(const float* __restrict__ p){
  float4 v0 = *(const float4*)p;
  float4 v1 = *(const float4*)(p + 4);
  uint4 o;
  o.x = (u32)f2b(v0.x) | ((u32)f2b(v0.y) << 16);
  o.y = (u32)f2b(v0.z) | ((u32)f2b(v0.w) << 16);
  o.z = (u32)f2b(v1.x) | ((u32)f2b(v1.y) << 16);
  o.w = (u32)f2b(v1.z) | ((u32)f2b(v1.w) << 16);
  return o;
}
__device__ __forceinline__ void stageA_f32(u16* lds, const float* __restrict__ src,
                                           int mbase, int Nn, int tid){
  #pragma unroll
  for (int i = 0; i < 8; i++){
    int chunk = tid + 256*i;
    int r = chunk >> 4;
    int c = chunk & 15;
    uint4 v = {0u,0u,0u,0u};
    int gr = mbase + r;
    if (gr < Nn) v = cvt8(src + (size_t)gr*HD + c*8);
    *(uint4*)(lds + (r*16 + (c ^ (r & 15)))*8) = v;
  }
}
__device__ __forceinline__ void stageB_f32(u16* lds, const float* __restrict__ w, int tid){
  #pragma unroll
  for (int i = 0; i < 8; i++){
    int chunk = tid + 256*i;
    int r = chunk >> 4;
    int c = chunk & 15;
    *(uint4*)(lds + (r*16 + (c ^ (r & 15)))*8) = cvt8(w + r*HD + c*8);
  }
}
__device__ __forceinline__ void mfma_tile(const u16* Als, const u16* Bls,
                                          int m0, int lane, f32x4 acc[2][8]){
  int quad = lane >> 4, lr = lane & 15;
  #pragma unroll
  for (int ks = 0; ks < 4; ks++){
    int q = ks*4 + quad;
    short8 a[2], b[8];
    #pragma unroll
    for (int rt = 0; rt < 2; rt++){
      int row = m0 + rt*16 + lr;
      a[rt] = *(const short8*)(Als + (row*16 + (q ^ lr))*8);
    }
    #pragma unroll
    for (int ct = 0; ct < 8; ct++){
      int row = ct*16 + lr;
      b[ct] = *(const short8*)(Bls + (row*16 + (q ^ lr))*8);
    }
    #pragma unroll
    for (int rt = 0; rt < 2; rt++)
      #pragma unroll
      for (int ct = 0; ct < 8; ct++)
        acc[rt][ct] = __builtin_amdgcn_mfma_f32_16x16x32_bf16(a[rt], b[ct], acc[rt][ct], 0, 0, 0);
  }
}

// ---------------- lin1: xh(bf16) = f32(x) @ W^T + b ----------------
__global__ __launch_bounds__(256,2)
void k_gemm1(const float* __restrict__ A, const float* __restrict__ W, const float* __restrict__ bias,
             int Nn, u16* __restrict__ out)
{
  __shared__ __align__(16) u16 Als[128*128];
  __shared__ __align__(16) u16 Bls[128*128];
  int tid = threadIdx.x;
  int lane = tid & 63, wave = tid >> 6;
  int m0 = wave*32, mbase = blockIdx.x*128;
  int quad = lane >> 4, lr = lane & 15;
  f32x4 acc[2][8];
  #pragma unroll
  for (int rt=0;rt<2;rt++)
    #pragma unroll
    for (int ct=0;ct<8;ct++) acc[rt][ct] = (f32x4){0.f,0.f,0.f,0.f};
  stageA_f32(Als, A, mbase, Nn, tid);
  stageB_f32(Bls, W, tid);
  __syncthreads();
  mfma_tile(Als, Bls, m0, lane, acc);
  float bcol[8];
  #pragma unroll
  for (int ct=0;ct<8;ct++) bcol[ct] = bias[ct*16+lr];
  #pragma unroll
  for (int rt=0;rt<2;rt++)
    #pragma unroll
    for (int ct=0;ct<8;ct++)
      #pragma unroll
      for (int r=0;r<4;r++){
        int grow = mbase + m0 + rt*16 + quad*4 + r;
        if (grow < Nn) out[(size_t)grow*HD + ct*16+lr] = f2b(sane(acc[rt][ct][r] + bcol[ct]));
      }
}

// ---------------- fused layer: in-LDS aggregation + 5 GEMMs + elu mix -------
__global__ __launch_bounds__(256,2)
void k_layer2(const u16* __restrict__ X, const int* __restrict__ rowptr, const int* __restrict__ csr,
              const float* __restrict__ sarr, const float* __restrict__ darr,
              const float* __restrict__ dis, const float* __restrict__ dinv,
              const float* __restrict__ gcnW, const float* __restrict__ gcnB,
              const float* __restrict__ Ws, const float* __restrict__ Wn,
              const float* __restrict__ ginW, const float* __restrict__ ginB,
              const float* __restrict__ gatW,
              const float* __restrict__ sm, int layer, int Nn, u16* __restrict__ out)
{
  __shared__ __align__(16) u16 At[128*128];
  __shared__ __align__(16) u16 Bt[128*128];
  int tid = threadIdx.x;
  int lane = tid & 63, wave = tid >> 6;
  int m0 = wave*32, mbase = blockIdx.x*128;
  int quad = lane >> 4, lr = lane & 15;
  int fc = lane >> 2;             // feature chunk of this lane's pair
  int fo = (2*lane) & 7;          // offset within chunk
  float w0 = sm[layer*4+0], w1 = sm[layer*4+1], w2 = sm[layer*4+2], w3 = sm[layer*4+3];
  float e1 = sm[17 + layer];

  f32x4 mix[2][8];
  f32x4 acc[2][8];
  float b0reg[2][4];
  #pragma unroll
  for (int rt=0;rt<2;rt++)
    #pragma unroll
    for (int r=0;r<4;r++) b0reg[rt][r] = 0.f;

  // ================= phase 1: GCN =================
  for (int n = 0; n < 32; n++){
    int v = mbase + m0 + n;
    float q0 = 0.f, q1 = 0.f, qd = 0.f;
    if (v < Nn){
      int beg = rowptr[v], end = rowptr[v+1];
      for (int e = beg; e < end; e++){
        int sv = csr[e];
        float ds = dis[sv];
        u32 xv = *(const u32*)(X + (size_t)sv*HD + lane*2);
        q0 = fmaf(ds, b2f((u16)(xv & 0xffff)), q0);
        q1 = fmaf(ds, b2f((u16)(xv >> 16)),    q1);
        qd += ds;
      }
      float dv = dis[v];
      q0 *= dv; q1 *= dv; qd *= dv;
    }
    if (((n & 15) >> 2) == quad) b0reg[n >> 4][n & 3] = qd;
    int row = m0 + n;
    *(u32*)(At + (row*16 + (fc ^ (row & 15)))*8 + fo) =
      (u32)f2b(q0) | ((u32)f2b(q1) << 16);
  }
  stageB_f32(Bt, gcnW + layer*16384, tid);
  __syncthreads();
  #pragma unroll
  for (int rt=0;rt<2;rt++)
    #pragma unroll
    for (int ct=0;ct<8;ct++) acc[rt][ct] = (f32x4){0.f,0.f,0.f,0.f};
  mfma_tile(At, Bt, m0, lane, acc);
  {
    float gb[8];
    #pragma unroll
    for (int ct=0;ct<8;ct++) gb[ct] = gcnB[layer*HD + ct*16+lr];
    #pragma unroll
    for (int rt=0;rt<2;rt++)
      #pragma unroll
      for (int ct=0;ct<8;ct++)
        #pragma unroll
        for (int r=0;r<4;r++)
          mix[rt][ct][r] = w0 * eluf(acc[rt][ct][r] + b0reg[rt][r]*gb[ct]);
  }
  __syncthreads();

  // ================= phase 2: SAGE self =================
  stageA(At, X, mbase, Nn, tid);
  stageB_f32(Bt, Ws + layer*16384, tid);
  __syncthreads();
  #pragma unroll
  for (int rt=0;rt<2;rt++)
    #pragma unroll
    for (int ct=0;ct<8;ct++) acc[rt][ct] = (f32x4){0.f,0.f,0.f,0.f};
  mfma_tile(At, Bt, m0, lane, acc);
  __syncthreads();

  // ================= phase 3: SAGE neighbor (mean) =================
  for (int n = 0; n < 32; n++){
    int v = mbase + m0 + n;
    float p0 = 0.f, p1 = 0.f;
    if (v < Nn){
      int beg = rowptr[v], end = rowptr[v+1];
      for (int e = beg; e < end; e++){
        int sv = csr[e];
        u32 xv = *(const u32*)(X + (size_t)sv*HD + lane*2);
        p0 += b2f((u16)(xv & 0xffff));
        p1 += b2f((u16)(xv >> 16));
      }
      float di = dinv[v];
      p0 *= di; p1 *= di;
    }
    int row = m0 + n;
    *(u32*)(At + (row*16 + (fc ^ (row & 15)))*8 + fo) =
      (u32)f2b(p0) | ((u32)f2b(p1) << 16);
  }
  stageB_f32(Bt, Wn + layer*16384, tid);
  __syncthreads();
  mfma_tile(At, Bt, m0, lane, acc);   // accumulate onto self-part
  #pragma unroll
  for (int rt=0;rt<2;rt++)
    #pragma unroll
    for (int ct=0;ct<8;ct++)
      #pragma unroll
      for (int r=0;r<4;r++)
        mix[rt][ct][r] += w1 * eluf(acc[rt][ct][r]);
  __syncthreads();

  // ================= phase 4: GIN  ((1+eps)x + P) =================
  for (int n = 0; n < 32; n++){
    int v = mbase + m0 + n;
    float g0 = 0.f, g1 = 0.f;
    if (v < Nn){
      float p0 = 0.f, p1 = 0.f;
      int beg = rowptr[v], end = rowptr[v+1];
      for (int e = beg; e < end; e++){
        int sv = csr[e];
        u32 xv = *(const u32*)(X + (size_t)sv*HD + lane*2);
        p0 += b2f((u16)(xv & 0xffff));
        p1 += b2f((u16)(xv >> 16));
      }
      u32 xm = *(const u32*)(X + (size_t)v*HD + lane*2);
      g0 = fmaf(e1, b2f((u16)(xm & 0xffff)), p0);
      g1 = fmaf(e1, b2f((u16)(xm >> 16)),    p1);
    }
    int row = m0 + n;
    *(u32*)(At + (row*16 + (fc ^ (row & 15)))*8 + fo) =
      (u32)f2b(g0) | ((u32)f2b(g1) << 16);
  }
  stageB_f32(Bt, ginW + layer*16384, tid);
  __syncthreads();
  #pragma unroll
  for (int rt=0;rt<2;rt++)
    #pragma unroll
    for (int ct=0;ct<8;ct++) acc[rt][ct] = (f32x4){0.f,0.f,0.f,0.f};
  mfma_tile(At, Bt, m0, lane, acc);
  {
    float gib[8];
    #pragma unroll
    for (int ct=0;ct<8;ct++) gib[ct] = ginB[layer*HD + ct*16+lr];
    #pragma unroll
    for (int rt=0;rt<2;rt++)
      #pragma unroll
      for (int ct=0;ct<8;ct++)
        #pragma unroll
        for (int r=0;r<4;r++)
          mix[rt][ct][r] += w2 * eluf(acc[rt][ct][r] + gib[ct]);
  }
  __syncthreads();

  // ================= phase 5: GAT =================
  for (int n = 0; n < 32; n++){
    int v = mbase + m0 + n;
    float r0 = 0.f, r1 = 0.f;
    if (v < Nn){
      int beg = rowptr[v], end = rowptr[v+1];
      float dval = darr[v];
      float mloc = -1e30f;
      for (int e = beg; e < end; e++){
        float t = sarr[csr[e]] + dval;
        float lg = t > 0.f ? t : 0.2f*t;
        mloc = fmaxf(mloc, lg);
      }
      float z = 0.f;
      for (int e = beg; e < end; e++){
        int sv = csr[e];
        float t = sarr[sv] + dval;
        float lg = t > 0.f ? t : 0.2f*t;
        float ew = __expf(lg - mloc);
        u32 xv = *(const u32*)(X + (size_t)sv*HD + lane*2);
        r0 = fmaf(ew, b2f((u16)(xv & 0xffff)), r0);
        r1 = fmaf(ew, b2f((u16)(xv >> 16)),    r1);
        z += ew;
      }
      float zinv = 1.f/(z + 1e-16f);
      r0 *= zinv; r1 *= zinv;
    }
    int row = m0 + n;
    *(u32*)(At + (row*16 + (fc ^ (row & 15)))*8 + fo) =
      (u32)f2b(r0) | ((u32)f2b(r1) << 16);
  }
  stageB_f32(Bt, gatW + layer*16384, tid);
  __syncthreads();
  #pragma unroll
  for (int rt=0;rt<2;rt++)
    #pragma unroll
    for (int ct=0;ct<8;ct++) acc[rt][ct] = (f32x4){0.f,0.f,0.f,0.f};
  mfma_tile(At, Bt, m0, lane, acc);
  #pragma unroll
  for (int rt=0;rt<2;rt++)
    #pragma unroll
    for (int ct=0;ct<8;ct++)
      #pragma unroll
      for (int r=0;r<4;r++)
        mix[rt][ct][r] += w3 * eluf(acc[rt][ct][r]);

  // ================= store (bf16 intermediate) =================
  #pragma unroll
  for (int rt=0;rt<2;rt++)
    #pragma unroll
    for (int ct=0;ct<8;ct++)
      #pragma unroll
      for (int r=0;r<4;r++){
        int grow = mbase + m0 + rt*16 + quad*4 + r;
        if (grow < Nn) out[(size_t)grow*HD + ct*16+lr] = f2b(sane(mix[rt][ct][r]));
      }
}

// ---------------- skip-connect + layer aggregator (bf16 in/out) -------------
__global__ void k_combine(const u16* __restrict__ X1, const u16* __restrict__ X2, const u16* __restrict__ X3,
                          const float* __restrict__ sm, int total, u16* __restrict__ X5)
{
  int i = blockIdx.x*256 + threadIdx.x;
  if (i >= total) return;
  float c1 = sm[12], c2 = sm[13], la0 = sm[14], la1 = sm[15], la2 = sm[16];
  u32 u1 = ((const u32*)X1)[i], u2v = ((const u32*)X2)[i], u3 = ((const u32*)X3)[i];
  u32 outp = 0;
  #pragma unroll
  for (int h = 0; h < 2; h++){
    float a1 = b2f((u16)(h ? (u1  >> 16) : (u1  & 0xffff)));
    float a2 = b2f((u16)(h ? (u2v >> 16) : (u2v & 0xffff)));
    float a3 = b2f((u16)(h ? (u3  >> 16) : (u3  & 0xffff)));
    float t0 = a3, t1 = c1*a1, t2 = c2*a2;
    float smm = t0 + t1 + t2;
    float mx = fmaxf(fmaxf(t0,t1),t2);
    float mn = smm * (1.f/3.f);
    float r = la0*reluf(mx) + la1*reluf(mn) + la2*reluf(smm);
    outp |= ((u32)f2b(sane(r))) << (16*h);
  }
  ((u32*)X5)[i] = outp;
}

// ---------------- classifier: out(f32) = x5(bf16) @ ncW^T(f32) + ncb --------
__global__ __launch_bounds__(256)
void k_nc(const u16* __restrict__ X5, const float* __restrict__ W, const float* __restrict__ bias,
          int Nn, float* __restrict__ out)
{
  __shared__ __align__(16) u16 xs[32*136];
  __shared__ __align__(16) float wn[40*132];
  __shared__ float bs[40];
  int t = threadIdx.x;
  int nb = blockIdx.x*32;
  #pragma unroll
  for (int i = 0; i < 2; i++){
    int chunk = t + 256*i;
    int r = chunk >> 4, c = chunk & 15;
    uint4 v = {0u,0u,0u,0u};
    int gr = nb + r;
    if (gr < Nn) v = *(const uint4*)(X5 + (size_t)gr*HD + c*8);
    *(uint4*)(xs + r*136 + c*8) = v;
  }
  #pragma unroll
  for (int i = 0; i < 5; i++){
    int chunk = t + 256*i;           // 1280 float4 chunks = 40*32
    int r = chunk >> 5, c = chunk & 31;
    *(float4*)(wn + r*132 + c*4) = *(const float4*)(W + r*HD + c*4);
  }
  if (t < 40) bs[t] = bias[t];
  __syncthreads();
  int nl = t >> 3, cg = t & 7;
  float acc[5];
  #pragma unroll
  for (int j = 0; j < 5; j++) acc[j] = bs[cg + 8*j];
  for (int k = 0; k < 128; k++){
    float xv = b2f(xs[nl*136 + k]);
    #pragma unroll
    for (int j = 0; j < 5; j++)
      acc[j] = fmaf(xv, wn[(cg + 8*j)*132 + k], acc[j]);
  }
  int gr = nb + nl;
  if (gr < Nn){
    #pragma unroll
    for (int j = 0; j < 5; j++)
      out[(size_t)gr*40 + cg + 8*j] = sane(acc[j]);
  }
}

// ---------------- host ----------------
extern "C" void kernel_launch(void* const* d_in, const int* in_sizes, int n_in,
                              void* d_out, int out_size, void* d_ws, size_t ws_size,
                              hipStream_t stream)
{
  (void)n_in; (void)out_size; (void)ws_size;
  const int N = in_sizes[0] / HD;
  const int E = in_sizes[1] / 2;
  const float* x      = (const float*)d_in[0];
  const int*   ei     = (const int*)d_in[1];
  const float* na_a   = (const float*)d_in[2];
  const float* sc_a   = (const float*)d_in[3];
  const float* la_a   = (const float*)d_in[4];
  const float* lin1W  = (const float*)d_in[5];
  const float* lin1b  = (const float*)d_in[6];
  const float* gcnW   = (const float*)d_in[7];
  const float* gcnB   = (const float*)d_in[8];
  const float* sageWs = (const float*)d_in[9];
  const float* sageWn = (const float*)d_in[10];
  const float* ginW   = (const float*)d_in[11];
  const float* ginB   = (const float*)d_in[12];
  const float* ginE   = (const float*)d_in[13];
  const float* gatW   = (const float*)d_in[14];
  const float* gatAs  = (const float*)d_in[15];
  const float* gatAd  = (const float*)d_in[16];
  const float* ncW    = (const float*)d_in[17];
  const float* ncB    = (const float*)d_in[18];

  char* base = (char*)d_ws;
  size_t off = 0;
  auto alloc = [&](size_t b) -> void* {
    void* p = base + off;
    off += (b + 255) & ~(size_t)255;
    return p;
  };
  // workspace total ~43 MB
  float* smalls = (float*)alloc(4096);
  int*   cnt    = (int*)alloc((size_t)N*4);
  int*   rowptr = (int*)alloc(((size_t)N+1)*4);
  int*   cursor = (int*)alloc((size_t)N*4);
  float* dis    = (float*)alloc((size_t)N*4);
  float* dinv   = (float*)alloc((size_t)N*4);
  float* sarr   = (float*)alloc((size_t)N*4);
  float* darr   = (float*)alloc((size_t)N*4);
  int*   csr    = (int*)alloc((size_t)E*4);
  u16*   xh     = (u16*)alloc((size_t)N*HD*2);   // h after lin1; reused as x3
  u16*   x1     = (u16*)alloc((size_t)N*HD*2);   // layer-1 out; reused as X5
  u16*   x2     = (u16*)alloc((size_t)N*HD*2);   // layer-2 out

  hipMemsetAsync(cnt, 0, (size_t)N*4, stream);
  k_small<<<1,128,0,stream>>>(na_a, sc_a, la_a, gatW, gatAs, gatAd, ginE, smalls);
  int ebl = (E + 255)/256;
  k_count<<<ebl,256,0,stream>>>(ei, E, cnt);
  k_scan<<<1,1024,0,stream>>>(cnt, rowptr, cursor, N);
  int nbl = (N + 255)/256;
  k_nodeinit<<<nbl,256,0,stream>>>(cnt, N, dis, dinv);
  k_fill<<<ebl,256,0,stream>>>(ei, E, cursor, csr);
  int gbl = (N + 127)/128;
  k_gemm1<<<gbl,256,0,stream>>>(x, lin1W, lin1b, N, xh);
  const u16* xc = xh;
  u16* outs[3] = {x1, x2, xh};    // x3 reuses xh (dead after layer 0)
  int wbl = (N + 3)/4;
  for (int l = 0; l < 3; l++){
    k_sd<<<wbl,256,0,stream>>>(xc, smalls, l, N, sarr, darr);
    k_layer2<<<gbl,256,0,stream>>>(xc, rowptr, csr, sarr, darr, dis, dinv,
                                   gcnW, gcnB, sageWs, sageWn, ginW, ginB, gatW,
                                   smalls, l, N, outs[l]);
    xc = outs[l];
  }
  int cbl = (N*64 + 255)/256;
  k_combine<<<cbl,256,0,stream>>>(x1, x2, xh, smalls, N*64, x1);  // X5 in-place
  int ncbl = (N + 31)/32;
  k_nc<<<ncbl,256,0,stream>>>(x1, ncW, ncB, N, (float*)d_out);
}

// Round 4
// 861.841 us; speedup vs baseline: 5.1524x; 5.1524x over previous
//
#include <hip/hip_runtime.h>

typedef unsigned short u16;
typedef unsigned int u32;
typedef __attribute__((ext_vector_type(8))) short short8;
typedef __attribute__((ext_vector_type(4))) float f32x4;

#define HD 128

__device__ inline float b2f(u16 u){ u32 v = ((u32)u) << 16; return __uint_as_float(v); }
__device__ inline u16 f2b(float f){
  u32 u = __float_as_uint(f);
  u32 r = (u + 0x7fffu + ((u >> 16) & 1u)) >> 16;
  return (u16)r;
}
__device__ inline u32 pack2(float a, float b){ return (u32)f2b(a) | ((u32)f2b(b) << 16); }
__device__ inline float lo2f(u32 w){ return b2f((u16)(w & 0xffff)); }
__device__ inline float hi2f(u32 w){ return b2f((u16)(w >> 16)); }
__device__ inline float eluf(float x){ return x > 0.f ? x : __expf(x) - 1.f; }
__device__ inline float reluf(float x){ return x > 0.f ? x : 0.f; }
__device__ inline float sane(float x){
  if (!(x == x)) return 0.f;
  return fminf(fmaxf(x, -1e30f), 1e30f);
}

// ---------------- small precompute ----------------
__global__ void k_small(const float* __restrict__ na_a, const float* __restrict__ sc_a,
                        const float* __restrict__ la_a, const float* __restrict__ gatW,
                        const float* __restrict__ gat_as, const float* __restrict__ gat_ad,
                        const float* __restrict__ gin_eps, float* __restrict__ sm)
{
  int t = threadIdx.x;
  if (t == 0){
    for (int l = 0; l < 3; l++){
      float a[4]; float mx = -1e30f;
      for (int i = 0; i < 4; i++){ a[i] = na_a[l*4+i]; mx = fmaxf(mx, a[i]); }
      float ssum = 0.f;
      for (int i = 0; i < 4; i++){ a[i] = __expf(a[i]-mx); ssum += a[i]; }
      for (int i = 0; i < 4; i++) sm[l*4+i] = a[i]/ssum;
    }
    for (int r = 0; r < 2; r++){
      float a0 = sc_a[r*2], a1 = sc_a[r*2+1];
      float mx = fmaxf(a0,a1);
      float e0 = __expf(a0-mx), e1 = __expf(a1-mx);
      sm[12+r] = e1/(e0+e1);
    }
    {
      float a0=la_a[0], a1=la_a[1], a2=la_a[2];
      float mx = fmaxf(fmaxf(a0,a1),a2);
      float e0=__expf(a0-mx), e1=__expf(a1-mx), e2=__expf(a2-mx);
      float ssum = e0+e1+e2;
      sm[14]=e0/ssum; sm[15]=e1/ssum; sm[16]=e2/ssum;
    }
    for (int l=0;l<3;l++) sm[17+l] = 1.f + gin_eps[l];
  }
  if (t < 128){
    for (int l=0;l<3;l++){
      float a1=0.f, a2=0.f;
      for (int k=0;k<128;k++){
        float wv = gatW[l*16384 + k*128 + t];
        a1 = fmaf(wv, gat_as[l*128+k], a1);
        a2 = fmaf(wv, gat_ad[l*128+k], a2);
      }
      sm[32  + l*128 + t] = a1;
      sm[416 + l*128 + t] = a2;
    }
  }
}

// ---------------- CSR build ----------------
__global__ void k_count(const int* __restrict__ ei, int E, int* __restrict__ cnt){
  int e = blockIdx.x*256 + threadIdx.x;
  if (e < E) atomicAdd(&cnt[ei[E + e]], 1);
}

__global__ void k_scan(const int* __restrict__ cnt, int* __restrict__ rowptr,
                       int* __restrict__ cursor, int Nn)
{
  __shared__ int part[1024];
  int t = threadIdx.x;
  int chunk = (Nn + 1023) >> 10;
  int base = t*chunk;
  int lim = min(base + chunk, Nn);
  int s = 0;
  for (int i = base; i < lim; i++) s += cnt[i];
  part[t] = s;
  __syncthreads();
  for (int off = 1; off < 1024; off <<= 1){
    int add = (t >= off) ? part[t - off] : 0;
    __syncthreads();
    part[t] += add;
    __syncthreads();
  }
  int run = part[t] - s;
  for (int i = base; i < lim; i++){
    rowptr[i] = run; cursor[i] = run; run += cnt[i];
  }
  if (t == 1023) rowptr[Nn] = part[1023];
}

__global__ void k_nodeinit(const int* __restrict__ cnt, int Nn,
                           float* __restrict__ dis, float* __restrict__ dinv){
  int v = blockIdx.x*256 + threadIdx.x;
  if (v < Nn){
    int c = cnt[v];
    float f = (float)c;
    dis[v]  = c > 0 ? 1.f/sqrtf(f) : 0.f;
    dinv[v] = 1.f/fmaxf(f, 1.f);
  }
}

__global__ void k_fill(const int* __restrict__ ei, int E,
                       int* __restrict__ cursor, int* __restrict__ csr){
  int e = blockIdx.x*256 + threadIdx.x;
  if (e < E){
    int sv = ei[e], dv = ei[E + e];
    int pos = atomicAdd(&cursor[dv], 1);
    csr[pos] = sv;
  }
}

// ---------------- per-node GAT scalars: s = x.ws, d = x.wd (X is bf16) ------
__global__ __launch_bounds__(256)
void k_sd(const u16* __restrict__ X, const float* __restrict__ sm, int layer, int Nn,
          float* __restrict__ sout, float* __restrict__ dout)
{
  int wv = blockIdx.x*4 + (threadIdx.x >> 6);
  if (wv >= Nn) return;
  int lane = threadIdx.x & 63;
  u32 xv = *(const u32*)(X + (size_t)wv*HD + lane*2);
  float x0 = lo2f(xv), x1 = hi2f(xv);
  const float* wsv = sm + 32  + layer*128;
  const float* wdv = sm + 416 + layer*128;
  float ps = x0*wsv[2*lane] + x1*wsv[2*lane+1];
  float pd = x0*wdv[2*lane] + x1*wdv[2*lane+1];
  #pragma unroll
  for (int off = 32; off > 0; off >>= 1){
    ps += __shfl_xor(ps, off);
    pd += __shfl_xor(pd, off);
  }
  if (lane == 0){ sout[wv] = ps; dout[wv] = pd; }
}

// ---------------- combined aggregation: one wave per dst node ----------------
// Single X-gather pass produces: Qb = dis[v]*sum(dis[sv]*x), Pb = sum(x),
// Rb = sum(alpha*x), b0 = dis[v]*sum(dis[sv]).
__global__ __launch_bounds__(256)
void k_agg(const u16* __restrict__ X, const int* __restrict__ rowptr, const int* __restrict__ csr,
           const float* __restrict__ sarr, const float* __restrict__ darr,
           const float* __restrict__ dis, int Nn,
           u16* __restrict__ Qb, u16* __restrict__ Pb, u16* __restrict__ Rb,
           float* __restrict__ b0)
{
  int wv = blockIdx.x*4 + (threadIdx.x >> 6);
  if (wv >= Nn) return;
  int lane = threadIdx.x & 63;
  int beg = rowptr[wv], end = rowptr[wv+1];
  float dval = darr[wv];
  // pass 1: exact segment max of leaky_relu(s[src]+d[v]) (lane-parallel)
  float mloc = -3.4e38f;
  for (int e = beg + lane; e < end; e += 64){
    float t = sarr[csr[e]] + dval;
    float lg = t > 0.f ? t : 0.2f*t;
    mloc = fmaxf(mloc, lg);
  }
  #pragma unroll
  for (int off = 32; off > 0; off >>= 1) mloc = fmaxf(mloc, __shfl_xor(mloc, off));
  // pass 2: single gather of X[sv], all weighted sums together
  float p0=0.f,p1=0.f,q0=0.f,q1=0.f,r0=0.f,r1=0.f,z=0.f,qd=0.f;
  for (int e = beg; e < end; e++){
    int sv = csr[e];
    float t = sarr[sv] + dval;
    float lg = t > 0.f ? t : 0.2f*t;
    float ew = __expf(lg - mloc);
    float dsv = dis[sv];
    u32 xv = *(const u32*)(X + (size_t)sv*HD + lane*2);
    float x0 = lo2f(xv), x1 = hi2f(xv);
    p0 += x0; p1 += x1;
    q0 = fmaf(dsv, x0, q0); q1 = fmaf(dsv, x1, q1);
    r0 = fmaf(ew,  x0, r0); r1 = fmaf(ew,  x1, r1);
    z += ew; qd += dsv;
  }
  float disv = dis[wv];
  float zinv = 1.f/(z + 1e-16f);
  size_t o = (size_t)wv*HD + lane*2;
  *(u32*)(Qb + o) = pack2(disv*q0, disv*q1);
  *(u32*)(Pb + o) = pack2(p0, p1);
  *(u32*)(Rb + o) = pack2(zinv*r0, zinv*r1);
  if (lane == 0) b0[wv] = disv*qd;
}

// ---------------- MFMA GEMM helpers (XOR-swizzled LDS, 16x16x32 bf16) -------
__device__ __forceinline__ void stageA(u16* lds, const u16* __restrict__ src,
                                       int mbase, int Nn, int tid){
  #pragma unroll
  for (int i = 0; i < 8; i++){
    int chunk = tid + 256*i;
    int r = chunk >> 4;
    int c = chunk & 15;
    uint4 v = {0u,0u,0u,0u};
    int gr = mbase + r;
    if (gr < Nn) v = *(const uint4*)(src + (size_t)gr*HD + c*8);
    *(uint4*)(lds + (r*16 + (c ^ (r & 15)))*8) = v;
  }
}
// bf16 source with per-row f32 scale (SAGE mean: scale = 1/deg)
__device__ __forceinline__ void stageA_scale(u16* lds, const u16* __restrict__ src,
                                             const float* __restrict__ scale,
                                             int mbase, int Nn, int tid){
  #pragma unroll
  for (int i = 0; i < 8; i++){
    int chunk = tid + 256*i;
    int r = chunk >> 4;
    int c = chunk & 15;
    uint4 v = {0u,0u,0u,0u};
    int gr = mbase + r;
    if (gr < Nn){
      uint4 raw = *(const uint4*)(src + (size_t)gr*HD + c*8);
      float s = scale[gr];
      v.x = pack2(lo2f(raw.x)*s, hi2f(raw.x)*s);
      v.y = pack2(lo2f(raw.y)*s, hi2f(raw.y)*s);
      v.z = pack2(lo2f(raw.z)*s, hi2f(raw.z)*s);
      v.w = pack2(lo2f(raw.w)*s, hi2f(raw.w)*s);
    }
    *(uint4*)(lds + (r*16 + (c ^ (r & 15)))*8) = v;
  }
}
// GIN tile: g = e1*x + psum
__device__ __forceinline__ void stageA_gin(u16* lds, const u16* __restrict__ X,
                                           const u16* __restrict__ Pb, float e1,
                                           int mbase, int Nn, int tid){
  #pragma unroll
  for (int i = 0; i < 8; i++){
    int chunk = tid + 256*i;
    int r = chunk >> 4;
    int c = chunk & 15;
    uint4 v = {0u,0u,0u,0u};
    int gr = mbase + r;
    if (gr < Nn){
      uint4 xr = *(const uint4*)(X  + (size_t)gr*HD + c*8);
      uint4 pr = *(const uint4*)(Pb + (size_t)gr*HD + c*8);
      v.x = pack2(fmaf(e1, lo2f(xr.x), lo2f(pr.x)), fmaf(e1, hi2f(xr.x), hi2f(pr.x)));
      v.y = pack2(fmaf(e1, lo2f(xr.y), lo2f(pr.y)), fmaf(e1, hi2f(xr.y), hi2f(pr.y)));
      v.z = pack2(fmaf(e1, lo2f(xr.z), lo2f(pr.z)), fmaf(e1, hi2f(xr.z), hi2f(pr.z)));
      v.w = pack2(fmaf(e1, lo2f(xr.w), lo2f(pr.w)), fmaf(e1, hi2f(xr.w), hi2f(pr.w)));
    }
    *(uint4*)(lds + (r*16 + (c ^ (r & 15)))*8) = v;
  }
}
// f32 weight -> bf16 LDS
__device__ __forceinline__ uint4 cvt8(const float* __restrict__ p){
  float4 v0 = *(const float4*)p;
  float4 v1 = *(const float4*)(p + 4);
  uint4 o;
  o.x = pack2(v0.x, v0.y);
  o.y = pack2(v0.z, v0.w);
  o.z = pack2(v1.x, v1.y);
  o.w = pack2(v1.z, v1.w);
  return o;
}
__device__ __forceinline__ void stageA_f32(u16* lds, const float* __restrict__ src,
                                           int mbase, int Nn, int tid){
  #pragma unroll
  for (int i = 0; i < 8; i++){
    int chunk = tid + 256*i;
    int r = chunk >> 4;
    int c = chunk & 15;
    uint4 v = {0u,0u,0u,0u};
    int gr = mbase + r;
    if (gr < Nn) v = cvt8(src + (size_t)gr*HD + c*8);
    *(uint4*)(lds + (r*16 + (c ^ (r & 15)))*8) = v;
  }
}
__device__ __forceinline__ void stageB_f32(u16* lds, const float* __restrict__ w, int tid){
  #pragma unroll
  for (int i = 0; i < 8; i++){
    int chunk = tid + 256*i;
    int r = chunk >> 4;
    int c = chunk & 15;
    *(uint4*)(lds + (r*16 + (c ^ (r & 15)))*8) = cvt8(w + r*HD + c*8);
  }
}
__device__ __forceinline__ void mfma_tile(const u16* Als, const u16* Bls,
                                          int m0, int lane, f32x4 acc[2][8]){
  int quad = lane >> 4, lr = lane & 15;
  #pragma unroll
  for (int ks = 0; ks < 4; ks++){
    int q = ks*4 + quad;
    short8 a[2], b[8];
    #pragma unroll
    for (int rt = 0; rt < 2; rt++){
      int row = m0 + rt*16 + lr;
      a[rt] = *(const short8*)(Als + (row*16 + (q ^ lr))*8);
    }
    #pragma unroll
    for (int ct = 0; ct < 8; ct++){
      int row = ct*16 + lr;
      b[ct] = *(const short8*)(Bls + (row*16 + (q ^ lr))*8);
    }
    #pragma unroll
    for (int rt = 0; rt < 2; rt++)
      #pragma unroll
      for (int ct = 0; ct < 8; ct++)
        acc[rt][ct] = __builtin_amdgcn_mfma_f32_16x16x32_bf16(a[rt], b[ct], acc[rt][ct], 0, 0, 0);
  }
}

// ---------------- lin1: xh(bf16) = f32(x) @ W^T + b ----------------
__global__ __launch_bounds__(256,2)
void k_gemm1(const float* __restrict__ A, const float* __restrict__ W, const float* __restrict__ bias,
             int Nn, u16* __restrict__ out)
{
  __shared__ __align__(16) u16 Als[128*128];
  __shared__ __align__(16) u16 Bls[128*128];
  int tid = threadIdx.x;
  int lane = tid & 63, wave = tid >> 6;
  int m0 = wave*32, mbase = blockIdx.x*128;
  int quad = lane >> 4, lr = lane & 15;
  f32x4 acc[2][8];
  #pragma unroll
  for (int rt=0;rt<2;rt++)
    #pragma unroll
    for (int ct=0;ct<8;ct++) acc[rt][ct] = (f32x4){0.f,0.f,0.f,0.f};
  stageA_f32(Als, A, mbase, Nn, tid);
  stageB_f32(Bls, W, tid);
  __syncthreads();
  mfma_tile(Als, Bls, m0, lane, acc);
  float bcol[8];
  #pragma unroll
  for (int ct=0;ct<8;ct++) bcol[ct] = bias[ct*16+lr];
  #pragma unroll
  for (int rt=0;rt<2;rt++)
    #pragma unroll
    for (int ct=0;ct<8;ct++)
      #pragma unroll
      for (int r=0;r<4;r++){
        int grow = mbase + m0 + rt*16 + quad*4 + r;
        if (grow < Nn) out[(size_t)grow*HD + ct*16+lr] = f2b(sane(acc[rt][ct][r] + bcol[ct]));
      }
}

// ---------------- fused layer (GEMM-only): 5 GEMMs + elu mix ----------------
__global__ __launch_bounds__(256,2)
void k_layer3(const u16* __restrict__ X, const u16* __restrict__ Qb,
              const u16* __restrict__ Pb, const u16* __restrict__ Rb,
              const float* __restrict__ dinv, const float* __restrict__ b0,
              const float* __restrict__ gcnW, const float* __restrict__ gcnB,
              const float* __restrict__ Ws, const float* __restrict__ Wn,
              const float* __restrict__ ginW, const float* __restrict__ ginB,
              const float* __restrict__ gatW,
              const float* __restrict__ sm, int layer, int Nn, u16* __restrict__ out)
{
  __shared__ __align__(16) u16 At[128*128];
  __shared__ __align__(16) u16 Bt[128*128];
  int tid = threadIdx.x;
  int lane = tid & 63, wave = tid >> 6;
  int m0 = wave*32, mbase = blockIdx.x*128;
  int quad = lane >> 4, lr = lane & 15;
  float w0 = sm[layer*4+0], w1 = sm[layer*4+1], w2 = sm[layer*4+2], w3 = sm[layer*4+3];
  float e1 = sm[17 + layer];

  f32x4 mix[2][8];
  f32x4 acc[2][8];
  float b0r[2][4];
  #pragma unroll
  for (int rt=0;rt<2;rt++)
    #pragma unroll
    for (int r=0;r<4;r++){
      int grow = mbase + m0 + rt*16 + quad*4 + r;
      b0r[rt][r] = (grow < Nn) ? b0[grow] : 0.f;
    }

  // ---- op0: GCN  (Qb @ gcnW^T, + b0*gcn_b) ----
  stageA(At, Qb, mbase, Nn, tid);
  stageB_f32(Bt, gcnW + layer*16384, tid);
  __syncthreads();
  #pragma unroll
  for (int rt=0;rt<2;rt++)
    #pragma unroll
    for (int ct=0;ct<8;ct++) acc[rt][ct] = (f32x4){0.f,0.f,0.f,0.f};
  mfma_tile(At, Bt, m0, lane, acc);
  {
    float gb[8];
    #pragma unroll
    for (int ct=0;ct<8;ct++) gb[ct] = gcnB[layer*HD + ct*16+lr];
    #pragma unroll
    for (int rt=0;rt<2;rt++)
      #pragma unroll
      for (int ct=0;ct<8;ct++)
        #pragma unroll
        for (int r=0;r<4;r++)
          mix[rt][ct][r] = w0 * eluf(acc[rt][ct][r] + b0r[rt][r]*gb[ct]);
  }
  __syncthreads();

  // ---- op1: SAGE  (X @ Ws^T + (Pb*dinv) @ Wn^T) ----
  stageA(At, X, mbase, Nn, tid);
  stageB_f32(Bt, Ws + layer*16384, tid);
  __syncthreads();
  #pragma unroll
  for (int rt=0;rt<2;rt++)
    #pragma unroll
    for (int ct=0;ct<8;ct++) acc[rt][ct] = (f32x4){0.f,0.f,0.f,0.f};
  mfma_tile(At, Bt, m0, lane, acc);
  __syncthreads();
  stageA_scale(At, Pb, dinv, mbase, Nn, tid);
  stageB_f32(Bt, Wn + layer*16384, tid);
  __syncthreads();
  mfma_tile(At, Bt, m0, lane, acc);
  #pragma unroll
  for (int rt=0;rt<2;rt++)
    #pragma unroll
    for (int ct=0;ct<8;ct++)
      #pragma unroll
      for (int r=0;r<4;r++)
        mix[rt][ct][r] += w1 * eluf(acc[rt][ct][r]);
  __syncthreads();

  // ---- op2: GIN  ((e1*x + Psum) @ ginW^T + gin_b) ----
  stageA_gin(At, X, Pb, e1, mbase, Nn, tid);
  stageB_f32(Bt, ginW + layer*16384, tid);
  __syncthreads();
  #pragma unroll
  for (int rt=0;rt<2;rt++)
    #pragma unroll
    for (int ct=0;ct<8;ct++) acc[rt][ct] = (f32x4){0.f,0.f,0.f,0.f};
  mfma_tile(At, Bt, m0, lane, acc);
  {
    float gib[8];
    #pragma unroll
    for (int ct=0;ct<8;ct++) gib[ct] = ginB[layer*HD + ct*16+lr];
    #pragma unroll
    for (int rt=0;rt<2;rt++)
      #pragma unroll
      for (int ct=0;ct<8;ct++)
        #pragma unroll
        for (int r=0;r<4;r++)
          mix[rt][ct][r] += w2 * eluf(acc[rt][ct][r] + gib[ct]);
  }
  __syncthreads();

  // ---- op3: GAT  (Rb @ gatW^T) ----
  stageA(At, Rb, mbase, Nn, tid);
  stageB_f32(Bt, gatW + layer*16384, tid);
  __syncthreads();
  #pragma unroll
  for (int rt=0;rt<2;rt++)
    #pragma unroll
    for (int ct=0;ct<8;ct++) acc[rt][ct] = (f32x4){0.f,0.f,0.f,0.f};
  mfma_tile(At, Bt, m0, lane, acc);
  #pragma unroll
  for (int rt=0;rt<2;rt++)
    #pragma unroll
    for (int ct=0;ct<8;ct++)
      #pragma unroll
      for (int r=0;r<4;r++)
        mix[rt][ct][r] += w3 * eluf(acc[rt][ct][r]);

  // ---- store (bf16 intermediate) ----
  #pragma unroll
  for (int rt=0;rt<2;rt++)
    #pragma unroll
    for (int ct=0;ct<8;ct++)
      #pragma unroll
      for (int r=0;r<4;r++){
        int grow = mbase + m0 + rt*16 + quad*4 + r;
        if (grow < Nn) out[(size_t)grow*HD + ct*16+lr] = f2b(sane(mix[rt][ct][r]));
      }
}

// ---------------- skip-connect + layer aggregator (bf16 in/out) -------------
__global__ void k_combine(const u16* __restrict__ X1, const u16* __restrict__ X2, const u16* __restrict__ X3,
                          const float* __restrict__ sm, int total, u16* __restrict__ X5)
{
  int i = blockIdx.x*256 + threadIdx.x;
  if (i >= total) return;
  float c1 = sm[12], c2 = sm[13], la0 = sm[14], la1 = sm[15], la2 = sm[16];
  u32 u1 = ((const u32*)X1)[i], u2v = ((const u32*)X2)[i], u3 = ((const u32*)X3)[i];
  u32 outp = 0;
  #pragma unroll
  for (int h = 0; h < 2; h++){
    float a1 = h ? hi2f(u1)  : lo2f(u1);
    float a2 = h ? hi2f(u2v) : lo2f(u2v);
    float a3 = h ? hi2f(u3)  : lo2f(u3);
    float t0 = a3, t1 = c1*a1, t2 = c2*a2;
    float smm = t0 + t1 + t2;
    float mx = fmaxf(fmaxf(t0,t1),t2);
    float mn = smm * (1.f/3.f);
    float r = la0*reluf(mx) + la1*reluf(mn) + la2*reluf(smm);
    outp |= ((u32)f2b(sane(r))) << (16*h);
  }
  ((u32*)X5)[i] = outp;
}

// ---------------- classifier: out(f32) = x5(bf16) @ ncW^T(f32) + ncb --------
__global__ __launch_bounds__(256)
void k_nc(const u16* __restrict__ X5, const float* __restrict__ W, const float* __restrict__ bias,
          int Nn, float* __restrict__ out)
{
  __shared__ __align__(16) u16 xs[32*136];
  __shared__ __align__(16) float wn[40*132];
  __shared__ float bs[40];
  int t = threadIdx.x;
  int nb = blockIdx.x*32;
  #pragma unroll
  for (int i = 0; i < 2; i++){
    int chunk = t + 256*i;
    int r = chunk >> 4, c = chunk & 15;
    uint4 v = {0u,0u,0u,0u};
    int gr = nb + r;
    if (gr < Nn) v = *(const uint4*)(X5 + (size_t)gr*HD + c*8);
    *(uint4*)(xs + r*136 + c*8) = v;
  }
  #pragma unroll
  for (int i = 0; i < 5; i++){
    int chunk = t + 256*i;
    int r = chunk >> 5, c = chunk & 31;
    *(float4*)(wn + r*132 + c*4) = *(const float4*)(W + r*HD + c*4);
  }
  if (t < 40) bs[t] = bias[t];
  __syncthreads();
  int nl = t >> 3, cg = t & 7;
  float acc[5];
  #pragma unroll
  for (int j = 0; j < 5; j++) acc[j] = bs[cg + 8*j];
  for (int k = 0; k < 128; k++){
    float xv = b2f(xs[nl*136 + k]);
    #pragma unroll
    for (int j = 0; j < 5; j++)
      acc[j] = fmaf(xv, wn[(cg + 8*j)*132 + k], acc[j]);
  }
  int gr = nb + nl;
  if (gr < Nn){
    #pragma unroll
    for (int j = 0; j < 5; j++)
      out[(size_t)gr*40 + cg + 8*j] = sane(acc[j]);
  }
}

// ---------------- host ----------------
extern "C" void kernel_launch(void* const* d_in, const int* in_sizes, int n_in,
                              void* d_out, int out_size, void* d_ws, size_t ws_size,
                              hipStream_t stream)
{
  (void)n_in; (void)out_size; (void)ws_size;
  const int N = in_sizes[0] / HD;
  const int E = in_sizes[1] / 2;
  const float* x      = (const float*)d_in[0];
  const int*   ei     = (const int*)d_in[1];
  const float* na_a   = (const float*)d_in[2];
  const float* sc_a   = (const float*)d_in[3];
  const float* la_a   = (const float*)d_in[4];
  const float* lin1W  = (const float*)d_in[5];
  const float* lin1b  = (const float*)d_in[6];
  const float* gcnW   = (const float*)d_in[7];
  const float* gcnB   = (const float*)d_in[8];
  const float* sageWs = (const float*)d_in[9];
  const float* sageWn = (const float*)d_in[10];
  const float* ginW   = (const float*)d_in[11];
  const float* ginB   = (const float*)d_in[12];
  const float* ginE   = (const float*)d_in[13];
  const float* gatW   = (const float*)d_in[14];
  const float* gatAs  = (const float*)d_in[15];
  const float* gatAd  = (const float*)d_in[16];
  const float* ncW    = (const float*)d_in[17];
  const float* ncB    = (const float*)d_in[18];

  char* base = (char*)d_ws;
  size_t off = 0;
  auto alloc = [&](size_t b) -> void* {
    void* p = base + off;
    off += (b + 255) & ~(size_t)255;
    return p;
  };
  // workspace total ~82 MB
  float* smalls = (float*)alloc(4096);
  int*   cnt    = (int*)alloc((size_t)N*4);
  int*   rowptr = (int*)alloc(((size_t)N+1)*4);
  int*   cursor = (int*)alloc((size_t)N*4);
  float* dis    = (float*)alloc((size_t)N*4);
  float* dinv   = (float*)alloc((size_t)N*4);
  float* sarr   = (float*)alloc((size_t)N*4);
  float* darr   = (float*)alloc((size_t)N*4);
  float* b0     = (float*)alloc((size_t)N*4);
  int*   csr    = (int*)alloc((size_t)E*4);
  u16*   xh     = (u16*)alloc((size_t)N*HD*2);   // h after lin1; reused as x3
  u16*   x1     = (u16*)alloc((size_t)N*HD*2);   // layer-1 out; reused as X5
  u16*   x2     = (u16*)alloc((size_t)N*HD*2);   // layer-2 out
  u16*   Qb     = (u16*)alloc((size_t)N*HD*2);   // dis-weighted sum (GCN)
  u16*   Pb     = (u16*)alloc((size_t)N*HD*2);   // plain sum (SAGE/GIN)
  u16*   Rb     = (u16*)alloc((size_t)N*HD*2);   // alpha-weighted sum (GAT)

  hipMemsetAsync(cnt, 0, (size_t)N*4, stream);
  k_small<<<1,128,0,stream>>>(na_a, sc_a, la_a, gatW, gatAs, gatAd, ginE, smalls);
  int ebl = (E + 255)/256;
  k_count<<<ebl,256,0,stream>>>(ei, E, cnt);
  k_scan<<<1,1024,0,stream>>>(cnt, rowptr, cursor, N);
  int nbl = (N + 255)/256;
  k_nodeinit<<<nbl,256,0,stream>>>(cnt, N, dis, dinv);
  k_fill<<<ebl,256,0,stream>>>(ei, E, cursor, csr);
  int gbl = (N + 127)/128;
  k_gemm1<<<gbl,256,0,stream>>>(x, lin1W, lin1b, N, xh);
  const u16* xc = xh;
  u16* outs[3] = {x1, x2, xh};    // x3 reuses xh (dead after layer 0)
  int wbl = (N + 3)/4;
  for (int l = 0; l < 3; l++){
    k_sd<<<wbl,256,0,stream>>>(xc, smalls, l, N, sarr, darr);
    k_agg<<<wbl,256,0,stream>>>(xc, rowptr, csr, sarr, darr, dis, N, Qb, Pb, Rb, b0);
    k_layer3<<<gbl,256,0,stream>>>(xc, Qb, Pb, Rb, dinv, b0,
                                   gcnW, gcnB, sageWs, sageWn, ginW, ginB, gatW,
                                   smalls, l, N, outs[l]);
    xc = outs[l];
  }
  int cbl = (N*64 + 255)/256;
  k_combine<<<cbl,256,0,stream>>>(x1, x2, xh, smalls, N*64, x1);  // X5 in-place
  int ncbl = (N + 31)/32;
  k_nc<<<ncbl,256,0,stream>>>(x1, ncW, ncB, N, (float*)d_out);
}

// Round 5
// 639.167 us; speedup vs baseline: 6.9474x; 1.3484x over previous
//
#include <hip/hip_runtime.h>

typedef unsigned short u16;
typedef unsigned int u32;
typedef __attribute__((ext_vector_type(8))) short short8;
typedef __attribute__((ext_vector_type(4))) float f32x4;

#define HD 128

__device__ inline float b2f(u16 u){ u32 v = ((u32)u) << 16; return __uint_as_float(v); }
__device__ inline u16 f2b(float f){
  u32 u = __float_as_uint(f);
  u32 r = (u + 0x7fffu + ((u >> 16) & 1u)) >> 16;
  return (u16)r;
}
__device__ inline u32 pack2(float a, float b){ return (u32)f2b(a) | ((u32)f2b(b) << 16); }
__device__ inline float lo2f(u32 w){ return b2f((u16)(w & 0xffff)); }
__device__ inline float hi2f(u32 w){ return b2f((u16)(w >> 16)); }
__device__ inline float eluf(float x){ return x > 0.f ? x : __expf(x) - 1.f; }
__device__ inline float reluf(float x){ return x > 0.f ? x : 0.f; }
__device__ inline float sane(float x){
  if (!(x == x)) return 0.f;
  return fminf(fmaxf(x, -1e30f), 1e30f);
}

// ---------------- small precompute ----------------
__global__ void k_small(const float* __restrict__ na_a, const float* __restrict__ sc_a,
                        const float* __restrict__ la_a, const float* __restrict__ gatW,
                        const float* __restrict__ gat_as, const float* __restrict__ gat_ad,
                        const float* __restrict__ gin_eps, float* __restrict__ sm)
{
  int t = threadIdx.x;
  if (t == 0){
    for (int l = 0; l < 3; l++){
      float a[4]; float mx = -1e30f;
      for (int i = 0; i < 4; i++){ a[i] = na_a[l*4+i]; mx = fmaxf(mx, a[i]); }
      float ssum = 0.f;
      for (int i = 0; i < 4; i++){ a[i] = __expf(a[i]-mx); ssum += a[i]; }
      for (int i = 0; i < 4; i++) sm[l*4+i] = a[i]/ssum;
    }
    for (int r = 0; r < 2; r++){
      float a0 = sc_a[r*2], a1 = sc_a[r*2+1];
      float mx = fmaxf(a0,a1);
      float e0 = __expf(a0-mx), e1 = __expf(a1-mx);
      sm[12+r] = e1/(e0+e1);
    }
    {
      float a0=la_a[0], a1=la_a[1], a2=la_a[2];
      float mx = fmaxf(fmaxf(a0,a1),a2);
      float e0=__expf(a0-mx), e1=__expf(a1-mx), e2=__expf(a2-mx);
      float ssum = e0+e1+e2;
      sm[14]=e0/ssum; sm[15]=e1/ssum; sm[16]=e2/ssum;
    }
    for (int l=0;l<3;l++) sm[17+l] = 1.f + gin_eps[l];
  }
  if (t < 128){
    for (int l=0;l<3;l++){
      float a1=0.f, a2=0.f;
      for (int k=0;k<128;k++){
        float wv = gatW[l*16384 + k*128 + t];
        a1 = fmaf(wv, gat_as[l*128+k], a1);
        a2 = fmaf(wv, gat_ad[l*128+k], a2);
      }
      sm[32  + l*128 + t] = a1;
      sm[416 + l*128 + t] = a2;
    }
  }
}

// ---------------- weight pre-conversion f32 -> bf16 -------------------------
__device__ __forceinline__ uint4 cvt8(const float* __restrict__ p){
  float4 v0 = *(const float4*)p;
  float4 v1 = *(const float4*)(p + 4);
  uint4 o;
  o.x = pack2(v0.x, v0.y);
  o.y = pack2(v0.z, v0.w);
  o.z = pack2(v1.x, v1.y);
  o.w = pack2(v1.z, v1.w);
  return o;
}
// wsb layout (16 matrices of 16384): [lin1 | gcn0..2 | Ws0..2 | Wn0..2 | gin0..2 | gat0..2]
__global__ void k_wcvt(const float* __restrict__ lin1W, const float* __restrict__ gcnW,
                       const float* __restrict__ Ws, const float* __restrict__ Wn,
                       const float* __restrict__ ginW, const float* __restrict__ gatW,
                       u16* __restrict__ wsb)
{
  int i = blockIdx.x*256 + threadIdx.x;   // 8-elem chunk id, 32768 total
  if (i >= 32768) return;
  int m = i >> 11;
  int off8 = (i & 2047) * 8;
  const float* src;
  if (m == 0)       src = lin1W + off8;
  else if (m < 4)   src = gcnW + (m-1)*16384 + off8;
  else if (m < 7)   src = Ws   + (m-4)*16384 + off8;
  else if (m < 10)  src = Wn   + (m-7)*16384 + off8;
  else if (m < 13)  src = ginW + (m-10)*16384 + off8;
  else              src = gatW + (m-13)*16384 + off8;
  *(uint4*)(wsb + (size_t)i*8) = cvt8(src);
}

// ---------------- CSR build (multi-block scan) ----------------
__global__ void k_count(const int* __restrict__ ei, int E, int* __restrict__ cnt){
  int e = blockIdx.x*256 + threadIdx.x;
  if (e < E) atomicAdd(&cnt[ei[E + e]], 1);
}

__global__ void k_scan1(const int* __restrict__ cnt, int Nn, int* __restrict__ bsum){
  __shared__ int red[256];
  int b = blockIdx.x, t = threadIdx.x;
  int base = b*1024 + t*4;
  int s = 0;
  #pragma unroll
  for (int k = 0; k < 4; k++){ int i = base + k; if (i < Nn) s += cnt[i]; }
  red[t] = s; __syncthreads();
  for (int off = 128; off; off >>= 1){
    if (t < off) red[t] += red[t + off];
    __syncthreads();
  }
  if (t == 0) bsum[b] = red[0];
}

__global__ void k_scan2(const int* __restrict__ bsum, int nb,
                        int* __restrict__ boffs, int* __restrict__ rowptr, int Nn){
  __shared__ int sc[1024];
  int t = threadIdx.x;
  int own = (t < nb) ? bsum[t] : 0;
  sc[t] = own;
  __syncthreads();
  for (int off = 1; off < 1024; off <<= 1){
    int add = (t >= off) ? sc[t - off] : 0;
    __syncthreads();
    sc[t] += add;
    __syncthreads();
  }
  if (t < nb) boffs[t] = sc[t] - own;
  if (t == 1023) rowptr[Nn] = sc[1023];
}

__global__ void k_scan3(const int* __restrict__ cnt, const int* __restrict__ boffs, int Nn,
                        int* __restrict__ rowptr, int* __restrict__ cursor,
                        float* __restrict__ dis, float* __restrict__ dinv){
  __shared__ int red[256];
  int b = blockIdx.x, t = threadIdx.x;
  int base = b*1024 + t*4;
  int c[4]; int s = 0;
  #pragma unroll
  for (int k = 0; k < 4; k++){ int i = base + k; c[k] = (i < Nn) ? cnt[i] : 0; s += c[k]; }
  red[t] = s; __syncthreads();
  for (int off = 1; off < 256; off <<= 1){
    int add = (t >= off) ? red[t - off] : 0;
    __syncthreads();
    red[t] += add;
    __syncthreads();
  }
  int run = red[t] - s + boffs[b];
  #pragma unroll
  for (int k = 0; k < 4; k++){
    int i = base + k;
    if (i < Nn){
      rowptr[i] = run; cursor[i] = run;
      float f = (float)c[k];
      dis[i]  = c[k] > 0 ? 1.f/sqrtf(f) : 0.f;
      dinv[i] = 1.f/fmaxf(f, 1.f);
      run += c[k];
    }
  }
}

__global__ void k_fill(const int* __restrict__ ei, int E,
                       int* __restrict__ cursor, int* __restrict__ csr){
  int e = blockIdx.x*256 + threadIdx.x;
  if (e < E){
    int sv = ei[e], dv = ei[E + e];
    int pos = atomicAdd(&cursor[dv], 1);
    csr[pos] = sv;
  }
}

// ---------------- per-node GAT scalars: s = x.ws, d = x.wd (X is bf16) ------
__global__ __launch_bounds__(256)
void k_sd(const u16* __restrict__ X, const float* __restrict__ sm, int layer, int Nn,
          float* __restrict__ sout, float* __restrict__ dout)
{
  int wv = blockIdx.x*4 + (threadIdx.x >> 6);
  if (wv >= Nn) return;
  int lane = threadIdx.x & 63;
  u32 xv = *(const u32*)(X + (size_t)wv*HD + lane*2);
  float x0 = lo2f(xv), x1 = hi2f(xv);
  const float* wsv = sm + 32  + layer*128;
  const float* wdv = sm + 416 + layer*128;
  float ps = x0*wsv[2*lane] + x1*wsv[2*lane+1];
  float pd = x0*wdv[2*lane] + x1*wdv[2*lane+1];
  #pragma unroll
  for (int off = 32; off > 0; off >>= 1){
    ps += __shfl_xor(ps, off);
    pd += __shfl_xor(pd, off);
  }
  if (lane == 0){ sout[wv] = ps; dout[wv] = pd; }
}

// ---------------- combined aggregation: one wave per dst, 4-edge groups -----
// lane = g*16+t: group g walks edges beg+g, beg+g+4, ...; lane covers 8 feats.
__global__ __launch_bounds__(256)
void k_agg(const u16* __restrict__ X, const int* __restrict__ rowptr, const int* __restrict__ csr,
           const float* __restrict__ sarr, const float* __restrict__ darr,
           const float* __restrict__ dis, int Nn,
           u16* __restrict__ Qb, u16* __restrict__ Pb, u16* __restrict__ Rb,
           float* __restrict__ b0)
{
  int wv = blockIdx.x*4 + (threadIdx.x >> 6);
  if (wv >= Nn) return;
  int lane = threadIdx.x & 63;
  int g = lane >> 4, t = lane & 15;
  int beg = rowptr[wv], end = rowptr[wv+1];
  float dval = darr[wv];
  // pass 1: exact segment max of leaky_relu(s[src]+d[v]) (64-lane parallel)
  float mloc = -3.4e38f;
  for (int e = beg + lane; e < end; e += 64){
    float s = sarr[csr[e]] + dval;
    float lg = s > 0.f ? s : 0.2f*s;
    mloc = fmaxf(mloc, lg);
  }
  #pragma unroll
  for (int off = 32; off > 0; off >>= 1) mloc = fmaxf(mloc, __shfl_xor(mloc, off));
  // pass 2: 4 edges in flight (one per group), single gather of X rows
  float p[8], q[8], r[8];
  #pragma unroll
  for (int k = 0; k < 8; k++){ p[k] = 0.f; q[k] = 0.f; r[k] = 0.f; }
  float z = 0.f, qd = 0.f;
  for (int e = beg + g; e < end; e += 4){
    int sv = csr[e];
    float s = sarr[sv] + dval;
    float lg = s > 0.f ? s : 0.2f*s;
    float ew = __expf(lg - mloc);
    float dsv = dis[sv];
    uint4 xv = *(const uint4*)(X + (size_t)sv*HD + t*8);
    float xf[8] = {lo2f(xv.x),hi2f(xv.x),lo2f(xv.y),hi2f(xv.y),
                   lo2f(xv.z),hi2f(xv.z),lo2f(xv.w),hi2f(xv.w)};
    #pragma unroll
    for (int k = 0; k < 8; k++){
      p[k] += xf[k];
      q[k] = fmaf(dsv, xf[k], q[k]);
      r[k] = fmaf(ew,  xf[k], r[k]);
    }
    z += ew; qd += dsv;
  }
  // cross-group reduce (groups differ in bits 4,5 of lane)
  #pragma unroll
  for (int off = 16; off <= 32; off <<= 1){
    #pragma unroll
    for (int k = 0; k < 8; k++){
      p[k] += __shfl_xor(p[k], off);
      q[k] += __shfl_xor(q[k], off);
      r[k] += __shfl_xor(r[k], off);
    }
    z  += __shfl_xor(z, off);
    qd += __shfl_xor(qd, off);
  }
  if (g == 0){
    float disv = dis[wv];
    float zinv = 1.f/(z + 1e-16f);
    size_t o = (size_t)wv*HD + t*8;
    uint4 qo, po, ro;
    qo.x = pack2(disv*q[0], disv*q[1]); qo.y = pack2(disv*q[2], disv*q[3]);
    qo.z = pack2(disv*q[4], disv*q[5]); qo.w = pack2(disv*q[6], disv*q[7]);
    po.x = pack2(p[0], p[1]); po.y = pack2(p[2], p[3]);
    po.z = pack2(p[4], p[5]); po.w = pack2(p[6], p[7]);
    ro.x = pack2(zinv*r[0], zinv*r[1]); ro.y = pack2(zinv*r[2], zinv*r[3]);
    ro.z = pack2(zinv*r[4], zinv*r[5]); ro.w = pack2(zinv*r[6], zinv*r[7]);
    *(uint4*)(Qb + o) = qo;
    *(uint4*)(Pb + o) = po;
    *(uint4*)(Rb + o) = ro;
    if (t == 0) b0[wv] = disv*qd;
  }
}

// ---------------- MFMA GEMM helpers (XOR-swizzled LDS, 16x16x32 bf16) -------
__device__ __forceinline__ void stageA(u16* lds, const u16* __restrict__ src,
                                       int mbase, int Nn, int tid){
  #pragma unroll
  for (int i = 0; i < 8; i++){
    int chunk = tid + 256*i;
    int r = chunk >> 4;
    int c = chunk & 15;
    uint4 v = {0u,0u,0u,0u};
    int gr = mbase + r;
    if (gr < Nn) v = *(const uint4*)(src + (size_t)gr*HD + c*8);
    *(uint4*)(lds + (r*16 + (c ^ (r & 15)))*8) = v;
  }
}
__device__ __forceinline__ void stageB_bf(u16* lds, const u16* __restrict__ w, int tid){
  #pragma unroll
  for (int i = 0; i < 8; i++){
    int chunk = tid + 256*i;
    int r = chunk >> 4;
    int c = chunk & 15;
    *(uint4*)(lds + (r*16 + (c ^ (r & 15)))*8) = *(const uint4*)(w + r*HD + c*8);
  }
}
// bf16 source with per-row f32 scale (SAGE mean)
__device__ __forceinline__ void stageA_scale(u16* lds, const u16* __restrict__ src,
                                             const float* __restrict__ scale,
                                             int mbase, int Nn, int tid){
  #pragma unroll
  for (int i = 0; i < 8; i++){
    int chunk = tid + 256*i;
    int r = chunk >> 4;
    int c = chunk & 15;
    uint4 v = {0u,0u,0u,0u};
    int gr = mbase + r;
    if (gr < Nn){
      uint4 raw = *(const uint4*)(src + (size_t)gr*HD + c*8);
      float s = scale[gr];
      v.x = pack2(lo2f(raw.x)*s, hi2f(raw.x)*s);
      v.y = pack2(lo2f(raw.y)*s, hi2f(raw.y)*s);
      v.z = pack2(lo2f(raw.z)*s, hi2f(raw.z)*s);
      v.w = pack2(lo2f(raw.w)*s, hi2f(raw.w)*s);
    }
    *(uint4*)(lds + (r*16 + (c ^ (r & 15)))*8) = v;
  }
}
// GIN tile: g = e1*x + psum
__device__ __forceinline__ void stageA_gin(u16* lds, const u16* __restrict__ X,
                                           const u16* __restrict__ Pb, float e1,
                                           int mbase, int Nn, int tid){
  #pragma unroll
  for (int i = 0; i < 8; i++){
    int chunk = tid + 256*i;
    int r = chunk >> 4;
    int c = chunk & 15;
    uint4 v = {0u,0u,0u,0u};
    int gr = mbase + r;
    if (gr < Nn){
      uint4 xr = *(const uint4*)(X  + (size_t)gr*HD + c*8);
      uint4 pr = *(const uint4*)(Pb + (size_t)gr*HD + c*8);
      v.x = pack2(fmaf(e1, lo2f(xr.x), lo2f(pr.x)), fmaf(e1, hi2f(xr.x), hi2f(pr.x)));
      v.y = pack2(fmaf(e1, lo2f(xr.y), lo2f(pr.y)), fmaf(e1, hi2f(xr.y), hi2f(pr.y)));
      v.z = pack2(fmaf(e1, lo2f(xr.z), lo2f(pr.z)), fmaf(e1, hi2f(xr.z), hi2f(pr.z)));
      v.w = pack2(fmaf(e1, lo2f(xr.w), lo2f(pr.w)), fmaf(e1, hi2f(xr.w), hi2f(pr.w)));
    }
    *(uint4*)(lds + (r*16 + (c ^ (r & 15)))*8) = v;
  }
}
// f32 source (input x only)
__device__ __forceinline__ void stageA_f32(u16* lds, const float* __restrict__ src,
                                           int mbase, int Nn, int tid){
  #pragma unroll
  for (int i = 0; i < 8; i++){
    int chunk = tid + 256*i;
    int r = chunk >> 4;
    int c = chunk & 15;
    uint4 v = {0u,0u,0u,0u};
    int gr = mbase + r;
    if (gr < Nn) v = cvt8(src + (size_t)gr*HD + c*8);
    *(uint4*)(lds + (r*16 + (c ^ (r & 15)))*8) = v;
  }
}
__device__ __forceinline__ void mfma_tile(const u16* Als, const u16* Bls,
                                          int m0, int lane, f32x4 acc[2][8]){
  int quad = lane >> 4, lr = lane & 15;
  #pragma unroll
  for (int ks = 0; ks < 4; ks++){
    int q = ks*4 + quad;
    short8 a[2], b[8];
    #pragma unroll
    for (int rt = 0; rt < 2; rt++){
      int row = m0 + rt*16 + lr;
      a[rt] = *(const short8*)(Als + (row*16 + (q ^ lr))*8);
    }
    #pragma unroll
    for (int ct = 0; ct < 8; ct++){
      int row = ct*16 + lr;
      b[ct] = *(const short8*)(Bls + (row*16 + (q ^ lr))*8);
    }
    #pragma unroll
    for (int rt = 0; rt < 2; rt++)
      #pragma unroll
      for (int ct = 0; ct < 8; ct++)
        acc[rt][ct] = __builtin_amdgcn_mfma_f32_16x16x32_bf16(a[rt], b[ct], acc[rt][ct], 0, 0, 0);
  }
}

// ---------------- lin1: xh(bf16) = f32(x) @ W^T + b ----------------
__global__ __launch_bounds__(256,2)
void k_gemm1(const float* __restrict__ A, const u16* __restrict__ Wb, const float* __restrict__ bias,
             int Nn, u16* __restrict__ out)
{
  __shared__ __align__(16) u16 Als[128*128];
  __shared__ __align__(16) u16 Bls[128*128];
  int tid = threadIdx.x;
  int lane = tid & 63, wave = tid >> 6;
  int m0 = wave*32, mbase = blockIdx.x*128;
  int quad = lane >> 4, lr = lane & 15;
  f32x4 acc[2][8];
  #pragma unroll
  for (int rt=0;rt<2;rt++)
    #pragma unroll
    for (int ct=0;ct<8;ct++) acc[rt][ct] = (f32x4){0.f,0.f,0.f,0.f};
  stageA_f32(Als, A, mbase, Nn, tid);
  stageB_bf(Bls, Wb, tid);
  __syncthreads();
  mfma_tile(Als, Bls, m0, lane, acc);
  float bcol[8];
  #pragma unroll
  for (int ct=0;ct<8;ct++) bcol[ct] = bias[ct*16+lr];
  #pragma unroll
  for (int rt=0;rt<2;rt++)
    #pragma unroll
    for (int ct=0;ct<8;ct++)
      #pragma unroll
      for (int r=0;r<4;r++){
        int grow = mbase + m0 + rt*16 + quad*4 + r;
        if (grow < Nn) out[(size_t)grow*HD + ct*16+lr] = f2b(sane(acc[rt][ct][r] + bcol[ct]));
      }
}

// ---------------- fused layer (GEMM-only): 5 GEMMs + elu mix ----------------
__global__ __launch_bounds__(256,2)
void k_layer3(const u16* __restrict__ X, const u16* __restrict__ Qb,
              const u16* __restrict__ Pb, const u16* __restrict__ Rb,
              const float* __restrict__ dinv, const float* __restrict__ b0,
              const u16* __restrict__ wsb,
              const float* __restrict__ gcnB, const float* __restrict__ ginB,
              const float* __restrict__ sm, int layer, int Nn, u16* __restrict__ out)
{
  __shared__ __align__(16) u16 At[128*128];
  __shared__ __align__(16) u16 Bt[128*128];
  int tid = threadIdx.x;
  int lane = tid & 63, wave = tid >> 6;
  int m0 = wave*32, mbase = blockIdx.x*128;
  int quad = lane >> 4, lr = lane & 15;
  float w0 = sm[layer*4+0], w1 = sm[layer*4+1], w2 = sm[layer*4+2], w3 = sm[layer*4+3];
  float e1 = sm[17 + layer];
  const u16* gcnWb = wsb + (size_t)(1  + layer)*16384;
  const u16* WsWb  = wsb + (size_t)(4  + layer)*16384;
  const u16* WnWb  = wsb + (size_t)(7  + layer)*16384;
  const u16* ginWb = wsb + (size_t)(10 + layer)*16384;
  const u16* gatWb = wsb + (size_t)(13 + layer)*16384;

  f32x4 mix[2][8];
  f32x4 acc[2][8];
  float b0r[2][4];
  #pragma unroll
  for (int rt=0;rt<2;rt++)
    #pragma unroll
    for (int r=0;r<4;r++){
      int grow = mbase + m0 + rt*16 + quad*4 + r;
      b0r[rt][r] = (grow < Nn) ? b0[grow] : 0.f;
    }

  // ---- op0: GCN  (Qb @ gcnW^T, + b0*gcn_b) ----
  stageA(At, Qb, mbase, Nn, tid);
  stageB_bf(Bt, gcnWb, tid);
  __syncthreads();
  #pragma unroll
  for (int rt=0;rt<2;rt++)
    #pragma unroll
    for (int ct=0;ct<8;ct++) acc[rt][ct] = (f32x4){0.f,0.f,0.f,0.f};
  mfma_tile(At, Bt, m0, lane, acc);
  {
    float gb[8];
    #pragma unroll
    for (int ct=0;ct<8;ct++) gb[ct] = gcnB[layer*HD + ct*16+lr];
    #pragma unroll
    for (int rt=0;rt<2;rt++)
      #pragma unroll
      for (int ct=0;ct<8;ct++)
        #pragma unroll
        for (int r=0;r<4;r++)
          mix[rt][ct][r] = w0 * eluf(acc[rt][ct][r] + b0r[rt][r]*gb[ct]);
  }
  __syncthreads();

  // ---- op1: SAGE  (X @ Ws^T + (Pb*dinv) @ Wn^T) ----
  stageA(At, X, mbase, Nn, tid);
  stageB_bf(Bt, WsWb, tid);
  __syncthreads();
  #pragma unroll
  for (int rt=0;rt<2;rt++)
    #pragma unroll
    for (int ct=0;ct<8;ct++) acc[rt][ct] = (f32x4){0.f,0.f,0.f,0.f};
  mfma_tile(At, Bt, m0, lane, acc);
  __syncthreads();
  stageA_scale(At, Pb, dinv, mbase, Nn, tid);
  stageB_bf(Bt, WnWb, tid);
  __syncthreads();
  mfma_tile(At, Bt, m0, lane, acc);
  #pragma unroll
  for (int rt=0;rt<2;rt++)
    #pragma unroll
    for (int ct=0;ct<8;ct++)
      #pragma unroll
      for (int r=0;r<4;r++)
        mix[rt][ct][r] += w1 * eluf(acc[rt][ct][r]);
  __syncthreads();

  // ---- op2: GIN  ((e1*x + Psum) @ ginW^T + gin_b) ----
  stageA_gin(At, X, Pb, e1, mbase, Nn, tid);
  stageB_bf(Bt, ginWb, tid);
  __syncthreads();
  #pragma unroll
  for (int rt=0;rt<2;rt++)
    #pragma unroll
    for (int ct=0;ct<8;ct++) acc[rt][ct] = (f32x4){0.f,0.f,0.f,0.f};
  mfma_tile(At, Bt, m0, lane, acc);
  {
    float gib[8];
    #pragma unroll
    for (int ct=0;ct<8;ct++) gib[ct] = ginB[layer*HD + ct*16+lr];
    #pragma unroll
    for (int rt=0;rt<2;rt++)
      #pragma unroll
      for (int ct=0;ct<8;ct++)
        #pragma unroll
        for (int r=0;r<4;r++)
          mix[rt][ct][r] += w2 * eluf(acc[rt][ct][r] + gib[ct]);
  }
  __syncthreads();

  // ---- op3: GAT  (Rb @ gatW^T) ----
  stageA(At, Rb, mbase, Nn, tid);
  stageB_bf(Bt, gatWb, tid);
  __syncthreads();
  #pragma unroll
  for (int rt=0;rt<2;rt++)
    #pragma unroll
    for (int ct=0;ct<8;ct++) acc[rt][ct] = (f32x4){0.f,0.f,0.f,0.f};
  mfma_tile(At, Bt, m0, lane, acc);
  #pragma unroll
  for (int rt=0;rt<2;rt++)
    #pragma unroll
    for (int ct=0;ct<8;ct++)
      #pragma unroll
      for (int r=0;r<4;r++)
        mix[rt][ct][r] += w3 * eluf(acc[rt][ct][r]);

  // ---- store (bf16 intermediate) ----
  #pragma unroll
  for (int rt=0;rt<2;rt++)
    #pragma unroll
    for (int ct=0;ct<8;ct++)
      #pragma unroll
      for (int r=0;r<4;r++){
        int grow = mbase + m0 + rt*16 + quad*4 + r;
        if (grow < Nn) out[(size_t)grow*HD + ct*16+lr] = f2b(sane(mix[rt][ct][r]));
      }
}

// ---------------- skip-connect + layer aggregator (bf16 in/out) -------------
__global__ void k_combine(const u16* __restrict__ X1, const u16* __restrict__ X2, const u16* __restrict__ X3,
                          const float* __restrict__ sm, int total, u16* __restrict__ X5)
{
  int i = blockIdx.x*256 + threadIdx.x;
  if (i >= total) return;
  float c1 = sm[12], c2 = sm[13], la0 = sm[14], la1 = sm[15], la2 = sm[16];
  u32 u1 = ((const u32*)X1)[i], u2v = ((const u32*)X2)[i], u3 = ((const u32*)X3)[i];
  u32 outp = 0;
  #pragma unroll
  for (int h = 0; h < 2; h++){
    float a1 = h ? hi2f(u1)  : lo2f(u1);
    float a2 = h ? hi2f(u2v) : lo2f(u2v);
    float a3 = h ? hi2f(u3)  : lo2f(u3);
    float t0 = a3, t1 = c1*a1, t2 = c2*a2;
    float smm = t0 + t1 + t2;
    float mx = fmaxf(fmaxf(t0,t1),t2);
    float mn = smm * (1.f/3.f);
    float r = la0*reluf(mx) + la1*reluf(mn) + la2*reluf(smm);
    outp |= ((u32)f2b(sane(r))) << (16*h);
  }
  ((u32*)X5)[i] = outp;
}

// ---------------- classifier: out(f32) = x5(bf16) @ ncW^T(f32) + ncb --------
__global__ __launch_bounds__(256)
void k_nc(const u16* __restrict__ X5, const float* __restrict__ W, const float* __restrict__ bias,
          int Nn, float* __restrict__ out)
{
  __shared__ __align__(16) u16 xs[32*136];
  __shared__ __align__(16) float wn[40*132];
  __shared__ float bs[40];
  int t = threadIdx.x;
  int nb = blockIdx.x*32;
  #pragma unroll
  for (int i = 0; i < 2; i++){
    int chunk = t + 256*i;
    int r = chunk >> 4, c = chunk & 15;
    uint4 v = {0u,0u,0u,0u};
    int gr = nb + r;
    if (gr < Nn) v = *(const uint4*)(X5 + (size_t)gr*HD + c*8);
    *(uint4*)(xs + r*136 + c*8) = v;
  }
  #pragma unroll
  for (int i = 0; i < 5; i++){
    int chunk = t + 256*i;
    int r = chunk >> 5, c = chunk & 31;
    *(float4*)(wn + r*132 + c*4) = *(const float4*)(W + r*HD + c*4);
  }
  if (t < 40) bs[t] = bias[t];
  __syncthreads();
  int nl = t >> 3, cg = t & 7;
  float acc[5];
  #pragma unroll
  for (int j = 0; j < 5; j++) acc[j] = bs[cg + 8*j];
  for (int k = 0; k < 128; k++){
    float xv = b2f(xs[nl*136 + k]);
    #pragma unroll
    for (int j = 0; j < 5; j++)
      acc[j] = fmaf(xv, wn[(cg + 8*j)*132 + k], acc[j]);
  }
  int gr = nb + nl;
  if (gr < Nn){
    #pragma unroll
    for (int j = 0; j < 5; j++)
      out[(size_t)gr*40 + cg + 8*j] = sane(acc[j]);
  }
}

// ---------------- host ----------------
extern "C" void kernel_launch(void* const* d_in, const int* in_sizes, int n_in,
                              void* d_out, int out_size, void* d_ws, size_t ws_size,
                              hipStream_t stream)
{
  (void)n_in; (void)out_size; (void)ws_size;
  const int N = in_sizes[0] / HD;
  const int E = in_sizes[1] / 2;
  const float* x      = (const float*)d_in[0];
  const int*   ei     = (const int*)d_in[1];
  const float* na_a   = (const float*)d_in[2];
  const float* sc_a   = (const float*)d_in[3];
  const float* la_a   = (const float*)d_in[4];
  const float* lin1W  = (const float*)d_in[5];
  const float* lin1b  = (const float*)d_in[6];
  const float* gcnW   = (const float*)d_in[7];
  const float* gcnB   = (const float*)d_in[8];
  const float* sageWs = (const float*)d_in[9];
  const float* sageWn = (const float*)d_in[10];
  const float* ginW   = (const float*)d_in[11];
  const float* ginB   = (const float*)d_in[12];
  const float* ginE   = (const float*)d_in[13];
  const float* gatW   = (const float*)d_in[14];
  const float* gatAs  = (const float*)d_in[15];
  const float* gatAd  = (const float*)d_in[16];
  const float* ncW    = (const float*)d_in[17];
  const float* ncB    = (const float*)d_in[18];

  char* base = (char*)d_ws;
  size_t off = 0;
  auto alloc = [&](size_t b) -> void* {
    void* p = base + off;
    off += (b + 255) & ~(size_t)255;
    return p;
  };
  const int NB = (N + 1023) / 1024;      // scan blocks (<=1024 supported)
  float* smalls = (float*)alloc(4096);
  int*   cnt    = (int*)alloc((size_t)N*4);
  int*   rowptr = (int*)alloc(((size_t)N+1)*4);
  int*   cursor = (int*)alloc((size_t)N*4);
  int*   bsum   = (int*)alloc(4096);
  int*   boffs  = (int*)alloc(4096);
  float* dis    = (float*)alloc((size_t)N*4);
  float* dinv   = (float*)alloc((size_t)N*4);
  float* sarr   = (float*)alloc((size_t)N*4);
  float* darr   = (float*)alloc((size_t)N*4);
  float* b0     = (float*)alloc((size_t)N*4);
  int*   csr    = (int*)alloc((size_t)E*4);
  u16*   wsb    = (u16*)alloc((size_t)16*16384*2);   // bf16 weights
  u16*   xh     = (u16*)alloc((size_t)N*HD*2);   // h after lin1; reused as x3
  u16*   x1     = (u16*)alloc((size_t)N*HD*2);   // layer-1 out; reused as X5
  u16*   x2     = (u16*)alloc((size_t)N*HD*2);   // layer-2 out
  u16*   Qb     = (u16*)alloc((size_t)N*HD*2);
  u16*   Pb     = (u16*)alloc((size_t)N*HD*2);
  u16*   Rb     = (u16*)alloc((size_t)N*HD*2);

  hipMemsetAsync(cnt, 0, (size_t)N*4, stream);
  k_small<<<1,128,0,stream>>>(na_a, sc_a, la_a, gatW, gatAs, gatAd, ginE, smalls);
  k_wcvt<<<128,256,0,stream>>>(lin1W, gcnW, sageWs, sageWn, ginW, gatW, wsb);
  int ebl = (E + 255)/256;
  k_count<<<ebl,256,0,stream>>>(ei, E, cnt);
  k_scan1<<<NB,256,0,stream>>>(cnt, N, bsum);
  k_scan2<<<1,1024,0,stream>>>(bsum, NB, boffs, rowptr, N);
  k_scan3<<<NB,256,0,stream>>>(cnt, boffs, N, rowptr, cursor, dis, dinv);
  k_fill<<<ebl,256,0,stream>>>(ei, E, cursor, csr);
  int gbl = (N + 127)/128;
  k_gemm1<<<gbl,256,0,stream>>>(x, wsb, lin1b, N, xh);
  const u16* xc = xh;
  u16* outs[3] = {x1, x2, xh};    // x3 reuses xh (dead after layer 0)
  int wbl = (N + 3)/4;
  for (int l = 0; l < 3; l++){
    k_sd<<<wbl,256,0,stream>>>(xc, smalls, l, N, sarr, darr);
    k_agg<<<wbl,256,0,stream>>>(xc, rowptr, csr, sarr, darr, dis, N, Qb, Pb, Rb, b0);
    k_layer3<<<gbl,256,0,stream>>>(xc, Qb, Pb, Rb, dinv, b0, wsb,
                                   gcnB, ginB, smalls, l, N, outs[l]);
    xc = outs[l];
  }
  int cbl = (N*64 + 255)/256;
  k_combine<<<cbl,256,0,stream>>>(x1, x2, xh, smalls, N*64, x1);  // X5 in-place
  int ncbl = (N + 31)/32;
  k_nc<<<ncbl,256,0,stream>>>(x1, ncW, ncB, N, (float*)d_out);
}

// Round 6
// 583.940 us; speedup vs baseline: 7.6044x; 1.0946x over previous
//
#include <hip/hip_runtime.h>

typedef unsigned short u16;
typedef unsigned int u32;
typedef __attribute__((ext_vector_type(8))) short short8;
typedef __attribute__((ext_vector_type(4))) float f32x4;

#define HD 128

__device__ inline float b2f(u16 u){ u32 v = ((u32)u) << 16; return __uint_as_float(v); }
__device__ inline u16 f2b(float f){
  u32 u = __float_as_uint(f);
  u32 r = (u + 0x7fffu + ((u >> 16) & 1u)) >> 16;
  return (u16)r;
}
__device__ inline u32 pack2(float a, float b){ return (u32)f2b(a) | ((u32)f2b(b) << 16); }
__device__ inline float lo2f(u32 w){ return b2f((u16)(w & 0xffff)); }
__device__ inline float hi2f(u32 w){ return b2f((u16)(w >> 16)); }
__device__ inline float eluf(float x){ return x > 0.f ? x : __expf(x) - 1.f; }
__device__ inline float reluf(float x){ return x > 0.f ? x : 0.f; }
__device__ inline float sane(float x){
  if (!(x == x)) return 0.f;
  return fminf(fmaxf(x, -1e30f), 1e30f);
}

// ---------------- small precompute ----------------
__global__ void k_small(const float* __restrict__ na_a, const float* __restrict__ sc_a,
                        const float* __restrict__ la_a, const float* __restrict__ gatW,
                        const float* __restrict__ gat_as, const float* __restrict__ gat_ad,
                        const float* __restrict__ gin_eps, float* __restrict__ sm)
{
  int t = threadIdx.x;
  if (t == 0){
    for (int l = 0; l < 3; l++){
      float a[4]; float mx = -1e30f;
      for (int i = 0; i < 4; i++){ a[i] = na_a[l*4+i]; mx = fmaxf(mx, a[i]); }
      float ssum = 0.f;
      for (int i = 0; i < 4; i++){ a[i] = __expf(a[i]-mx); ssum += a[i]; }
      for (int i = 0; i < 4; i++) sm[l*4+i] = a[i]/ssum;
    }
    for (int r = 0; r < 2; r++){
      float a0 = sc_a[r*2], a1 = sc_a[r*2+1];
      float mx = fmaxf(a0,a1);
      float e0 = __expf(a0-mx), e1 = __expf(a1-mx);
      sm[12+r] = e1/(e0+e1);
    }
    {
      float a0=la_a[0], a1=la_a[1], a2=la_a[2];
      float mx = fmaxf(fmaxf(a0,a1),a2);
      float e0=__expf(a0-mx), e1=__expf(a1-mx), e2=__expf(a2-mx);
      float ssum = e0+e1+e2;
      sm[14]=e0/ssum; sm[15]=e1/ssum; sm[16]=e2/ssum;
    }
    for (int l=0;l<3;l++) sm[17+l] = 1.f + gin_eps[l];
  }
  if (t < 128){
    for (int l=0;l<3;l++){
      float a1=0.f, a2=0.f;
      for (int k=0;k<128;k++){
        float wv = gatW[l*16384 + k*128 + t];
        a1 = fmaf(wv, gat_as[l*128+k], a1);
        a2 = fmaf(wv, gat_ad[l*128+k], a2);
      }
      sm[32  + l*128 + t] = a1;
      sm[416 + l*128 + t] = a2;
    }
  }
}

// ---------------- weight pre-conversion f32 -> bf16 -------------------------
__device__ __forceinline__ uint4 cvt8(const float* __restrict__ p){
  float4 v0 = *(const float4*)p;
  float4 v1 = *(const float4*)(p + 4);
  uint4 o;
  o.x = pack2(v0.x, v0.y);
  o.y = pack2(v0.z, v0.w);
  o.z = pack2(v1.x, v1.y);
  o.w = pack2(v1.z, v1.w);
  return o;
}
// wsb layout (16 matrices of 16384): [lin1 | gcn0..2 | Ws0..2 | Wn0..2 | gin0..2 | gat0..2]
__global__ void k_wcvt(const float* __restrict__ lin1W, const float* __restrict__ gcnW,
                       const float* __restrict__ Ws, const float* __restrict__ Wn,
                       const float* __restrict__ ginW, const float* __restrict__ gatW,
                       u16* __restrict__ wsb)
{
  int i = blockIdx.x*256 + threadIdx.x;
  if (i >= 32768) return;
  int m = i >> 11;
  int off8 = (i & 2047) * 8;
  const float* src;
  if (m == 0)       src = lin1W + off8;
  else if (m < 4)   src = gcnW + (m-1)*16384 + off8;
  else if (m < 7)   src = Ws   + (m-4)*16384 + off8;
  else if (m < 10)  src = Wn   + (m-7)*16384 + off8;
  else if (m < 13)  src = ginW + (m-10)*16384 + off8;
  else              src = gatW + (m-13)*16384 + off8;
  *(uint4*)(wsb + (size_t)i*8) = cvt8(src);
}

// ---------------- CSR build (multi-block scan) ----------------
__global__ void k_count(const int* __restrict__ ei, int E, int* __restrict__ cnt){
  int e = blockIdx.x*256 + threadIdx.x;
  if (e < E) atomicAdd(&cnt[ei[E + e]], 1);
}

__global__ void k_scan1(const int* __restrict__ cnt, int Nn, int* __restrict__ bsum){
  __shared__ int red[256];
  int b = blockIdx.x, t = threadIdx.x;
  int base = b*1024 + t*4;
  int s = 0;
  #pragma unroll
  for (int k = 0; k < 4; k++){ int i = base + k; if (i < Nn) s += cnt[i]; }
  red[t] = s; __syncthreads();
  for (int off = 128; off; off >>= 1){
    if (t < off) red[t] += red[t + off];
    __syncthreads();
  }
  if (t == 0) bsum[b] = red[0];
}

__global__ void k_scan2(const int* __restrict__ bsum, int nb,
                        int* __restrict__ boffs, int* __restrict__ rowptr, int Nn){
  __shared__ int sc[1024];
  int t = threadIdx.x;
  int own = (t < nb) ? bsum[t] : 0;
  sc[t] = own;
  __syncthreads();
  for (int off = 1; off < 1024; off <<= 1){
    int add = (t >= off) ? sc[t - off] : 0;
    __syncthreads();
    sc[t] += add;
    __syncthreads();
  }
  if (t < nb) boffs[t] = sc[t] - own;
  if (t == 1023) rowptr[Nn] = sc[1023];
}

__global__ void k_scan3(const int* __restrict__ cnt, const int* __restrict__ boffs, int Nn,
                        int* __restrict__ rowptr, int* __restrict__ cursor,
                        float* __restrict__ dis, float* __restrict__ dinv){
  __shared__ int red[256];
  int b = blockIdx.x, t = threadIdx.x;
  int base = b*1024 + t*4;
  int c[4]; int s = 0;
  #pragma unroll
  for (int k = 0; k < 4; k++){ int i = base + k; c[k] = (i < Nn) ? cnt[i] : 0; s += c[k]; }
  red[t] = s; __syncthreads();
  for (int off = 1; off < 256; off <<= 1){
    int add = (t >= off) ? red[t - off] : 0;
    __syncthreads();
    red[t] += add;
    __syncthreads();
  }
  int run = red[t] - s + boffs[b];
  #pragma unroll
  for (int k = 0; k < 4; k++){
    int i = base + k;
    if (i < Nn){
      rowptr[i] = run; cursor[i] = run;
      float f = (float)c[k];
      dis[i]  = c[k] > 0 ? 1.f/sqrtf(f) : 0.f;
      dinv[i] = 1.f/fmaxf(f, 1.f);
      run += c[k];
    }
  }
}

__global__ void k_fill(const int* __restrict__ ei, int E,
                       int* __restrict__ cursor, int* __restrict__ csr){
  int e = blockIdx.x*256 + threadIdx.x;
  if (e < E){
    int sv = ei[e], dv = ei[E + e];
    int pos = atomicAdd(&cursor[dv], 1);
    csr[pos] = sv;
  }
}

// ---------------- per-node GAT scalars ----------------
__global__ __launch_bounds__(256)
void k_sd(const u16* __restrict__ X, const float* __restrict__ sm, int layer, int Nn,
          float* __restrict__ sout, float* __restrict__ dout)
{
  int wv = blockIdx.x*4 + (threadIdx.x >> 6);
  if (wv >= Nn) return;
  int lane = threadIdx.x & 63;
  u32 xv = *(const u32*)(X + (size_t)wv*HD + lane*2);
  float x0 = lo2f(xv), x1 = hi2f(xv);
  const float* wsv = sm + 32  + layer*128;
  const float* wdv = sm + 416 + layer*128;
  float ps = x0*wsv[2*lane] + x1*wsv[2*lane+1];
  float pd = x0*wdv[2*lane] + x1*wdv[2*lane+1];
  #pragma unroll
  for (int off = 32; off > 0; off >>= 1){
    ps += __shfl_xor(ps, off);
    pd += __shfl_xor(pd, off);
  }
  if (lane == 0){ sout[wv] = ps; dout[wv] = pd; }
}

// ---------------- combined aggregation: wave/dst, 4 groups, 2x unroll -------
__global__ __launch_bounds__(256)
void k_agg(const u16* __restrict__ X, const int* __restrict__ rowptr, const int* __restrict__ csr,
           const float* __restrict__ sarr, const float* __restrict__ darr,
           const float* __restrict__ dis, int Nn,
           u16* __restrict__ Qb, u16* __restrict__ Pb, u16* __restrict__ Rb,
           float* __restrict__ b0)
{
  int wv = blockIdx.x*4 + (threadIdx.x >> 6);
  if (wv >= Nn) return;
  int lane = threadIdx.x & 63;
  int g = lane >> 4, t = lane & 15;
  int beg = rowptr[wv], end = rowptr[wv+1];
  float dval = darr[wv];
  // pass 1: exact segment max
  float mloc = -3.4e38f;
  for (int e = beg + lane; e < end; e += 64){
    float s = sarr[csr[e]] + dval;
    float lg = s > 0.f ? s : 0.2f*s;
    mloc = fmaxf(mloc, lg);
  }
  #pragma unroll
  for (int off = 32; off > 0; off >>= 1) mloc = fmaxf(mloc, __shfl_xor(mloc, off));
  // pass 2: 8 edges in flight per wave (4 groups x 2 unroll)
  float p[8], q[8], r[8];
  #pragma unroll
  for (int k = 0; k < 8; k++){ p[k] = 0.f; q[k] = 0.f; r[k] = 0.f; }
  float z = 0.f, qd = 0.f;
  int e = beg + g;
  for (; e + 4 < end; e += 8){
    int sv0 = csr[e], sv1 = csr[e+4];
    float s0 = sarr[sv0] + dval, s1 = sarr[sv1] + dval;
    float dsv0 = dis[sv0], dsv1 = dis[sv1];
    uint4 xv0 = *(const uint4*)(X + (size_t)sv0*HD + t*8);
    uint4 xv1 = *(const uint4*)(X + (size_t)sv1*HD + t*8);
    float lg0 = s0 > 0.f ? s0 : 0.2f*s0;
    float lg1 = s1 > 0.f ? s1 : 0.2f*s1;
    float ew0 = __expf(lg0 - mloc), ew1 = __expf(lg1 - mloc);
    float xf0[8] = {lo2f(xv0.x),hi2f(xv0.x),lo2f(xv0.y),hi2f(xv0.y),
                    lo2f(xv0.z),hi2f(xv0.z),lo2f(xv0.w),hi2f(xv0.w)};
    float xf1[8] = {lo2f(xv1.x),hi2f(xv1.x),lo2f(xv1.y),hi2f(xv1.y),
                    lo2f(xv1.z),hi2f(xv1.z),lo2f(xv1.w),hi2f(xv1.w)};
    #pragma unroll
    for (int k = 0; k < 8; k++){
      p[k] += xf0[k] + xf1[k];
      q[k] = fmaf(dsv0, xf0[k], fmaf(dsv1, xf1[k], q[k]));
      r[k] = fmaf(ew0,  xf0[k], fmaf(ew1,  xf1[k], r[k]));
    }
    z += ew0 + ew1; qd += dsv0 + dsv1;
  }
  if (e < end){
    int sv = csr[e];
    float s = sarr[sv] + dval;
    float lg = s > 0.f ? s : 0.2f*s;
    float ew = __expf(lg - mloc);
    float dsv = dis[sv];
    uint4 xv = *(const uint4*)(X + (size_t)sv*HD + t*8);
    float xf[8] = {lo2f(xv.x),hi2f(xv.x),lo2f(xv.y),hi2f(xv.y),
                   lo2f(xv.z),hi2f(xv.z),lo2f(xv.w),hi2f(xv.w)};
    #pragma unroll
    for (int k = 0; k < 8; k++){
      p[k] += xf[k];
      q[k] = fmaf(dsv, xf[k], q[k]);
      r[k] = fmaf(ew,  xf[k], r[k]);
    }
    z += ew; qd += dsv;
  }
  // cross-group reduce
  #pragma unroll
  for (int off = 16; off <= 32; off <<= 1){
    #pragma unroll
    for (int k = 0; k < 8; k++){
      p[k] += __shfl_xor(p[k], off);
      q[k] += __shfl_xor(q[k], off);
      r[k] += __shfl_xor(r[k], off);
    }
    z  += __shfl_xor(z, off);
    qd += __shfl_xor(qd, off);
  }
  if (g == 0){
    float disv = dis[wv];
    float zinv = 1.f/(z + 1e-16f);
    size_t o = (size_t)wv*HD + t*8;
    uint4 qo, po, ro;
    qo.x = pack2(disv*q[0], disv*q[1]); qo.y = pack2(disv*q[2], disv*q[3]);
    qo.z = pack2(disv*q[4], disv*q[5]); qo.w = pack2(disv*q[6], disv*q[7]);
    po.x = pack2(p[0], p[1]); po.y = pack2(p[2], p[3]);
    po.z = pack2(p[4], p[5]); po.w = pack2(p[6], p[7]);
    ro.x = pack2(zinv*r[0], zinv*r[1]); ro.y = pack2(zinv*r[2], zinv*r[3]);
    ro.z = pack2(zinv*r[4], zinv*r[5]); ro.w = pack2(zinv*r[6], zinv*r[7]);
    *(uint4*)(Qb + o) = qo;
    *(uint4*)(Pb + o) = po;
    *(uint4*)(Rb + o) = ro;
    if (t == 0) b0[wv] = disv*qd;
  }
}

// ---------------- MFMA helpers, M=64 tile (XOR-swizzled LDS) ----------------
// A tile: 64 rows x 128 cols bf16 (16 KB); B tile: 128x128 (32 KB)
__device__ __forceinline__ void stageA64(u16* lds, const u16* __restrict__ src,
                                         int mbase, int Nn, int tid){
  #pragma unroll
  for (int i = 0; i < 4; i++){
    int chunk = tid + 256*i;
    int r = chunk >> 4;
    int c = chunk & 15;
    uint4 v = {0u,0u,0u,0u};
    int gr = mbase + r;
    if (gr < Nn) v = *(const uint4*)(src + (size_t)gr*HD + c*8);
    *(uint4*)(lds + (r*16 + (c ^ (r & 15)))*8) = v;
  }
}
__device__ __forceinline__ void stageA64_scale(u16* lds, const u16* __restrict__ src,
                                               const float* __restrict__ scale,
                                               int mbase, int Nn, int tid){
  #pragma unroll
  for (int i = 0; i < 4; i++){
    int chunk = tid + 256*i;
    int r = chunk >> 4;
    int c = chunk & 15;
    uint4 v = {0u,0u,0u,0u};
    int gr = mbase + r;
    if (gr < Nn){
      uint4 raw = *(const uint4*)(src + (size_t)gr*HD + c*8);
      float s = scale[gr];
      v.x = pack2(lo2f(raw.x)*s, hi2f(raw.x)*s);
      v.y = pack2(lo2f(raw.y)*s, hi2f(raw.y)*s);
      v.z = pack2(lo2f(raw.z)*s, hi2f(raw.z)*s);
      v.w = pack2(lo2f(raw.w)*s, hi2f(raw.w)*s);
    }
    *(uint4*)(lds + (r*16 + (c ^ (r & 15)))*8) = v;
  }
}
__device__ __forceinline__ void stageA64_gin(u16* lds, const u16* __restrict__ X,
                                             const u16* __restrict__ Pb, float e1,
                                             int mbase, int Nn, int tid){
  #pragma unroll
  for (int i = 0; i < 4; i++){
    int chunk = tid + 256*i;
    int r = chunk >> 4;
    int c = chunk & 15;
    uint4 v = {0u,0u,0u,0u};
    int gr = mbase + r;
    if (gr < Nn){
      uint4 xr = *(const uint4*)(X  + (size_t)gr*HD + c*8);
      uint4 pr = *(const uint4*)(Pb + (size_t)gr*HD + c*8);
      v.x = pack2(fmaf(e1, lo2f(xr.x), lo2f(pr.x)), fmaf(e1, hi2f(xr.x), hi2f(pr.x)));
      v.y = pack2(fmaf(e1, lo2f(xr.y), lo2f(pr.y)), fmaf(e1, hi2f(xr.y), hi2f(pr.y)));
      v.z = pack2(fmaf(e1, lo2f(xr.z), lo2f(pr.z)), fmaf(e1, hi2f(xr.z), hi2f(pr.z)));
      v.w = pack2(fmaf(e1, lo2f(xr.w), lo2f(pr.w)), fmaf(e1, hi2f(xr.w), hi2f(pr.w)));
    }
    *(uint4*)(lds + (r*16 + (c ^ (r & 15)))*8) = v;
  }
}
__device__ __forceinline__ void stageA64_f32(u16* lds, const float* __restrict__ src,
                                             int mbase, int Nn, int tid){
  #pragma unroll
  for (int i = 0; i < 4; i++){
    int chunk = tid + 256*i;
    int r = chunk >> 4;
    int c = chunk & 15;
    uint4 v = {0u,0u,0u,0u};
    int gr = mbase + r;
    if (gr < Nn) v = cvt8(src + (size_t)gr*HD + c*8);
    *(uint4*)(lds + (r*16 + (c ^ (r & 15)))*8) = v;
  }
}
__device__ __forceinline__ void stageB_bf(u16* lds, const u16* __restrict__ w, int tid){
  #pragma unroll
  for (int i = 0; i < 8; i++){
    int chunk = tid + 256*i;
    int r = chunk >> 4;
    int c = chunk & 15;
    *(uint4*)(lds + (r*16 + (c ^ (r & 15)))*8) = *(const uint4*)(w + r*HD + c*8);
  }
}
// wave computes 16 rows (m0 = wave*16) x 128 cols
__device__ __forceinline__ void mfma_tile64(const u16* Als, const u16* Bls,
                                            int m0, int lane, f32x4 acc[8]){
  int quad = lane >> 4, lr = lane & 15;
  #pragma unroll
  for (int ks = 0; ks < 4; ks++){
    int q = ks*4 + quad;
    short8 a, b[8];
    int row = m0 + lr;
    a = *(const short8*)(Als + (row*16 + (q ^ lr))*8);
    #pragma unroll
    for (int ct = 0; ct < 8; ct++){
      int brow = ct*16 + lr;
      b[ct] = *(const short8*)(Bls + (brow*16 + (q ^ lr))*8);
    }
    #pragma unroll
    for (int ct = 0; ct < 8; ct++)
      acc[ct] = __builtin_amdgcn_mfma_f32_16x16x32_bf16(a, b[ct], acc[ct], 0, 0, 0);
  }
}

// ---------------- lin1: xh(bf16) = f32(x) @ W^T + b  (M=64) ----------------
__global__ __launch_bounds__(256,3)
void k_gemm1(const float* __restrict__ A, const u16* __restrict__ Wb, const float* __restrict__ bias,
             int Nn, u16* __restrict__ out)
{
  __shared__ __align__(16) u16 Als[64*128];
  __shared__ __align__(16) u16 Bls[128*128];
  int tid = threadIdx.x;
  int lane = tid & 63, wave = tid >> 6;
  int m0 = wave*16, mbase = blockIdx.x*64;
  int quad = lane >> 4, lr = lane & 15;
  f32x4 acc[8];
  #pragma unroll
  for (int ct=0;ct<8;ct++) acc[ct] = (f32x4){0.f,0.f,0.f,0.f};
  stageA64_f32(Als, A, mbase, Nn, tid);
  stageB_bf(Bls, Wb, tid);
  __syncthreads();
  mfma_tile64(Als, Bls, m0, lane, acc);
  float bcol[8];
  #pragma unroll
  for (int ct=0;ct<8;ct++) bcol[ct] = bias[ct*16+lr];
  #pragma unroll
  for (int ct=0;ct<8;ct++)
    #pragma unroll
    for (int r=0;r<4;r++){
      int grow = mbase + m0 + quad*4 + r;
      if (grow < Nn) out[(size_t)grow*HD + ct*16+lr] = f2b(sane(acc[ct][r] + bcol[ct]));
    }
}

// ---------------- fused layer (GEMM-only, M=64): 5 GEMMs + elu mix ----------
__global__ __launch_bounds__(256,3)
void k_layer3(const u16* __restrict__ X, const u16* __restrict__ Qb,
              const u16* __restrict__ Pb, const u16* __restrict__ Rb,
              const float* __restrict__ dinv, const float* __restrict__ b0,
              const u16* __restrict__ wsb,
              const float* __restrict__ gcnB, const float* __restrict__ ginB,
              const float* __restrict__ sm, int layer, int Nn, u16* __restrict__ out)
{
  __shared__ __align__(16) u16 At[64*128];
  __shared__ __align__(16) u16 Bt[128*128];
  int tid = threadIdx.x;
  int lane = tid & 63, wave = tid >> 6;
  int m0 = wave*16, mbase = blockIdx.x*64;
  int quad = lane >> 4, lr = lane & 15;
  float w0 = sm[layer*4+0], w1 = sm[layer*4+1], w2 = sm[layer*4+2], w3 = sm[layer*4+3];
  float e1 = sm[17 + layer];
  const u16* gcnWb = wsb + (size_t)(1  + layer)*16384;
  const u16* WsWb  = wsb + (size_t)(4  + layer)*16384;
  const u16* WnWb  = wsb + (size_t)(7  + layer)*16384;
  const u16* ginWb = wsb + (size_t)(10 + layer)*16384;
  const u16* gatWb = wsb + (size_t)(13 + layer)*16384;

  f32x4 mix[8];
  f32x4 acc[8];
  float b0r[4];
  #pragma unroll
  for (int r=0;r<4;r++){
    int grow = mbase + m0 + quad*4 + r;
    b0r[r] = (grow < Nn) ? b0[grow] : 0.f;
  }

  // ---- op0: GCN ----
  stageA64(At, Qb, mbase, Nn, tid);
  stageB_bf(Bt, gcnWb, tid);
  __syncthreads();
  #pragma unroll
  for (int ct=0;ct<8;ct++) acc[ct] = (f32x4){0.f,0.f,0.f,0.f};
  mfma_tile64(At, Bt, m0, lane, acc);
  {
    float gb[8];
    #pragma unroll
    for (int ct=0;ct<8;ct++) gb[ct] = gcnB[layer*HD + ct*16+lr];
    #pragma unroll
    for (int ct=0;ct<8;ct++)
      #pragma unroll
      for (int r=0;r<4;r++)
        mix[ct][r] = w0 * eluf(acc[ct][r] + b0r[r]*gb[ct]);
  }
  __syncthreads();

  // ---- op1: SAGE ----
  stageA64(At, X, mbase, Nn, tid);
  stageB_bf(Bt, WsWb, tid);
  __syncthreads();
  #pragma unroll
  for (int ct=0;ct<8;ct++) acc[ct] = (f32x4){0.f,0.f,0.f,0.f};
  mfma_tile64(At, Bt, m0, lane, acc);
  __syncthreads();
  stageA64_scale(At, Pb, dinv, mbase, Nn, tid);
  stageB_bf(Bt, WnWb, tid);
  __syncthreads();
  mfma_tile64(At, Bt, m0, lane, acc);
  #pragma unroll
  for (int ct=0;ct<8;ct++)
    #pragma unroll
    for (int r=0;r<4;r++)
      mix[ct][r] += w1 * eluf(acc[ct][r]);
  __syncthreads();

  // ---- op2: GIN ----
  stageA64_gin(At, X, Pb, e1, mbase, Nn, tid);
  stageB_bf(Bt, ginWb, tid);
  __syncthreads();
  #pragma unroll
  for (int ct=0;ct<8;ct++) acc[ct] = (f32x4){0.f,0.f,0.f,0.f};
  mfma_tile64(At, Bt, m0, lane, acc);
  {
    float gib[8];
    #pragma unroll
    for (int ct=0;ct<8;ct++) gib[ct] = ginB[layer*HD + ct*16+lr];
    #pragma unroll
    for (int ct=0;ct<8;ct++)
      #pragma unroll
      for (int r=0;r<4;r++)
        mix[ct][r] += w2 * eluf(acc[ct][r] + gib[ct]);
  }
  __syncthreads();

  // ---- op3: GAT ----
  stageA64(At, Rb, mbase, Nn, tid);
  stageB_bf(Bt, gatWb, tid);
  __syncthreads();
  #pragma unroll
  for (int ct=0;ct<8;ct++) acc[ct] = (f32x4){0.f,0.f,0.f,0.f};
  mfma_tile64(At, Bt, m0, lane, acc);
  #pragma unroll
  for (int ct=0;ct<8;ct++)
    #pragma unroll
    for (int r=0;r<4;r++)
      mix[ct][r] += w3 * eluf(acc[ct][r]);

  // ---- store ----
  #pragma unroll
  for (int ct=0;ct<8;ct++)
    #pragma unroll
    for (int r=0;r<4;r++){
      int grow = mbase + m0 + quad*4 + r;
      if (grow < Nn) out[(size_t)grow*HD + ct*16+lr] = f2b(sane(mix[ct][r]));
    }
}

// ------- classifier with fused skip/layer-agg: out = combine(x1,x2,x3)@W^T+b -
__global__ __launch_bounds__(256)
void k_nc(const u16* __restrict__ X1, const u16* __restrict__ X2, const u16* __restrict__ X3,
          const float* __restrict__ W, const float* __restrict__ bias,
          const float* __restrict__ sm, int Nn, float* __restrict__ out)
{
  __shared__ __align__(16) u16 xs[32*136];
  __shared__ __align__(16) float wn[40*132];
  __shared__ float bs[40];
  int t = threadIdx.x;
  int nb = blockIdx.x*32;
  float c1 = sm[12], c2 = sm[13], la0 = sm[14], la1 = sm[15], la2 = sm[16];
  #pragma unroll
  for (int i = 0; i < 2; i++){
    int chunk = t + 256*i;
    int r = chunk >> 4, c = chunk & 15;
    uint4 v = {0u,0u,0u,0u};
    int gr = nb + r;
    if (gr < Nn){
      size_t o = (size_t)gr*HD + c*8;
      uint4 u1 = *(const uint4*)(X1 + o);
      uint4 u2 = *(const uint4*)(X2 + o);
      uint4 u3 = *(const uint4*)(X3 + o);
      u32* u1p = (u32*)&u1; u32* u2p = (u32*)&u2; u32* u3p = (u32*)&u3; u32* vp = (u32*)&v;
      #pragma unroll
      for (int k = 0; k < 4; k++){
        float o0, o1;
        {
          float a1 = lo2f(u1p[k]), a2 = lo2f(u2p[k]), a3 = lo2f(u3p[k]);
          float t0 = a3, t1 = c1*a1, t2 = c2*a2;
          float smm = t0 + t1 + t2;
          float mx = fmaxf(fmaxf(t0,t1),t2);
          o0 = la0*reluf(mx) + la1*reluf(smm*(1.f/3.f)) + la2*reluf(smm);
        }
        {
          float a1 = hi2f(u1p[k]), a2 = hi2f(u2p[k]), a3 = hi2f(u3p[k]);
          float t0 = a3, t1 = c1*a1, t2 = c2*a2;
          float smm = t0 + t1 + t2;
          float mx = fmaxf(fmaxf(t0,t1),t2);
          o1 = la0*reluf(mx) + la1*reluf(smm*(1.f/3.f)) + la2*reluf(smm);
        }
        vp[k] = pack2(sane(o0), sane(o1));
      }
    }
    *(uint4*)(xs + r*136 + c*8) = v;
  }
  #pragma unroll
  for (int i = 0; i < 5; i++){
    int chunk = t + 256*i;
    int r = chunk >> 5, c = chunk & 31;
    *(float4*)(wn + r*132 + c*4) = *(const float4*)(W + r*HD + c*4);
  }
  if (t < 40) bs[t] = bias[t];
  __syncthreads();
  int nl = t >> 3, cg = t & 7;
  float acc[5];
  #pragma unroll
  for (int j = 0; j < 5; j++) acc[j] = bs[cg + 8*j];
  for (int k = 0; k < 128; k++){
    float xv = b2f(xs[nl*136 + k]);
    #pragma unroll
    for (int j = 0; j < 5; j++)
      acc[j] = fmaf(xv, wn[(cg + 8*j)*132 + k], acc[j]);
  }
  int gr = nb + nl;
  if (gr < Nn){
    #pragma unroll
    for (int j = 0; j < 5; j++)
      out[(size_t)gr*40 + cg + 8*j] = sane(acc[j]);
  }
}

// ---------------- host ----------------
extern "C" void kernel_launch(void* const* d_in, const int* in_sizes, int n_in,
                              void* d_out, int out_size, void* d_ws, size_t ws_size,
                              hipStream_t stream)
{
  (void)n_in; (void)out_size; (void)ws_size;
  const int N = in_sizes[0] / HD;
  const int E = in_sizes[1] / 2;
  const float* x      = (const float*)d_in[0];
  const int*   ei     = (const int*)d_in[1];
  const float* na_a   = (const float*)d_in[2];
  const float* sc_a   = (const float*)d_in[3];
  const float* la_a   = (const float*)d_in[4];
  const float* lin1W  = (const float*)d_in[5];
  const float* lin1b  = (const float*)d_in[6];
  const float* gcnW   = (const float*)d_in[7];
  const float* gcnB   = (const float*)d_in[8];
  const float* sageWs = (const float*)d_in[9];
  const float* sageWn = (const float*)d_in[10];
  const float* ginW   = (const float*)d_in[11];
  const float* ginB   = (const float*)d_in[12];
  const float* ginE   = (const float*)d_in[13];
  const float* gatW   = (const float*)d_in[14];
  const float* gatAs  = (const float*)d_in[15];
  const float* gatAd  = (const float*)d_in[16];
  const float* ncW    = (const float*)d_in[17];
  const float* ncB    = (const float*)d_in[18];

  char* base = (char*)d_ws;
  size_t off = 0;
  auto alloc = [&](size_t b) -> void* {
    void* p = base + off;
    off += (b + 255) & ~(size_t)255;
    return p;
  };
  const int NB = (N + 1023) / 1024;
  float* smalls = (float*)alloc(4096);
  int*   cnt    = (int*)alloc((size_t)N*4);
  int*   rowptr = (int*)alloc(((size_t)N+1)*4);
  int*   cursor = (int*)alloc((size_t)N*4);
  int*   bsum   = (int*)alloc(4096);
  int*   boffs  = (int*)alloc(4096);
  float* dis    = (float*)alloc((size_t)N*4);
  float* dinv   = (float*)alloc((size_t)N*4);
  float* sarr   = (float*)alloc((size_t)N*4);
  float* darr   = (float*)alloc((size_t)N*4);
  float* b0     = (float*)alloc((size_t)N*4);
  int*   csr    = (int*)alloc((size_t)E*4);
  u16*   wsb    = (u16*)alloc((size_t)16*16384*2);
  u16*   xh     = (u16*)alloc((size_t)N*HD*2);   // h after lin1; reused as x3
  u16*   x1     = (u16*)alloc((size_t)N*HD*2);
  u16*   x2     = (u16*)alloc((size_t)N*HD*2);
  u16*   Qb     = (u16*)alloc((size_t)N*HD*2);
  u16*   Pb     = (u16*)alloc((size_t)N*HD*2);
  u16*   Rb     = (u16*)alloc((size_t)N*HD*2);

  hipMemsetAsync(cnt, 0, (size_t)N*4, stream);
  k_small<<<1,128,0,stream>>>(na_a, sc_a, la_a, gatW, gatAs, gatAd, ginE, smalls);
  k_wcvt<<<128,256,0,stream>>>(lin1W, gcnW, sageWs, sageWn, ginW, gatW, wsb);
  int ebl = (E + 255)/256;
  k_count<<<ebl,256,0,stream>>>(ei, E, cnt);
  k_scan1<<<NB,256,0,stream>>>(cnt, N, bsum);
  k_scan2<<<1,1024,0,stream>>>(bsum, NB, boffs, rowptr, N);
  k_scan3<<<NB,256,0,stream>>>(cnt, boffs, N, rowptr, cursor, dis, dinv);
  k_fill<<<ebl,256,0,stream>>>(ei, E, cursor, csr);
  int gbl64 = (N + 63)/64;
  k_gemm1<<<gbl64,256,0,stream>>>(x, wsb, lin1b, N, xh);
  const u16* xc = xh;
  u16* outs[3] = {x1, x2, xh};    // x3 reuses xh (dead after layer 0)
  int wbl = (N + 3)/4;
  for (int l = 0; l < 3; l++){
    k_sd<<<wbl,256,0,stream>>>(xc, smalls, l, N, sarr, darr);
    k_agg<<<wbl,256,0,stream>>>(xc, rowptr, csr, sarr, darr, dis, N, Qb, Pb, Rb, b0);
    k_layer3<<<gbl64,256,0,stream>>>(xc, Qb, Pb, Rb, dinv, b0, wsb,
                                     gcnB, ginB, smalls, l, N, outs[l]);
    xc = outs[l];
  }
  int ncbl = (N + 31)/32;
  k_nc<<<ncbl,256,0,stream>>>(x1, x2, xh, ncW, ncB, smalls, N, (float*)d_out);
}

// Round 7
// 578.371 us; speedup vs baseline: 7.6777x; 1.0096x over previous
//
#include <hip/hip_runtime.h>

typedef unsigned short u16;
typedef unsigned int u32;
typedef __attribute__((ext_vector_type(8))) short short8;
typedef __attribute__((ext_vector_type(4))) float f32x4;
typedef __attribute__((ext_vector_type(2))) float f32x2;

#define HD 128

__device__ inline float b2f(u16 u){ u32 v = ((u32)u) << 16; return __uint_as_float(v); }
__device__ inline u16 f2b(float f){
  u32 u = __float_as_uint(f);
  u32 r = (u + 0x7fffu + ((u >> 16) & 1u)) >> 16;
  return (u16)r;
}
__device__ inline u32 pack2(float a, float b){ return (u32)f2b(a) | ((u32)f2b(b) << 16); }
__device__ inline float lo2f(u32 w){ return b2f((u16)(w & 0xffff)); }
__device__ inline float hi2f(u32 w){ return b2f((u16)(w >> 16)); }
__device__ inline float eluf(float x){ return x > 0.f ? x : __expf(x) - 1.f; }
__device__ inline float reluf(float x){ return x > 0.f ? x : 0.f; }
__device__ inline float sane(float x){
  if (!(x == x)) return 0.f;
  return fminf(fmaxf(x, -1e30f), 1e30f);
}
// async 16B global->LDS (lds base wave-uniform; lane i lands at base + i*16)
__device__ __forceinline__ void async16(const u16* g, u16* l){
  __builtin_amdgcn_global_load_lds((const __attribute__((address_space(1))) void*)g,
                                   (__attribute__((address_space(3))) void*)l, 16, 0, 0);
}

// ---------------- small precompute ----------------
__global__ void k_small(const float* __restrict__ na_a, const float* __restrict__ sc_a,
                        const float* __restrict__ la_a, const float* __restrict__ gatW,
                        const float* __restrict__ gat_as, const float* __restrict__ gat_ad,
                        const float* __restrict__ gin_eps, float* __restrict__ sm)
{
  int t = threadIdx.x;
  if (t == 0){
    for (int l = 0; l < 3; l++){
      float a[4]; float mx = -1e30f;
      for (int i = 0; i < 4; i++){ a[i] = na_a[l*4+i]; mx = fmaxf(mx, a[i]); }
      float ssum = 0.f;
      for (int i = 0; i < 4; i++){ a[i] = __expf(a[i]-mx); ssum += a[i]; }
      for (int i = 0; i < 4; i++) sm[l*4+i] = a[i]/ssum;
    }
    for (int r = 0; r < 2; r++){
      float a0 = sc_a[r*2], a1 = sc_a[r*2+1];
      float mx = fmaxf(a0,a1);
      float e0 = __expf(a0-mx), e1 = __expf(a1-mx);
      sm[12+r] = e1/(e0+e1);
    }
    {
      float a0=la_a[0], a1=la_a[1], a2=la_a[2];
      float mx = fmaxf(fmaxf(a0,a1),a2);
      float e0=__expf(a0-mx), e1=__expf(a1-mx), e2=__expf(a2-mx);
      float ssum = e0+e1+e2;
      sm[14]=e0/ssum; sm[15]=e1/ssum; sm[16]=e2/ssum;
    }
    for (int l=0;l<3;l++) sm[17+l] = 1.f + gin_eps[l];
  }
  if (t < 128){
    for (int l=0;l<3;l++){
      float a1=0.f, a2=0.f;
      for (int k=0;k<128;k++){
        float wv = gatW[l*16384 + k*128 + t];
        a1 = fmaf(wv, gat_as[l*128+k], a1);
        a2 = fmaf(wv, gat_ad[l*128+k], a2);
      }
      sm[32  + l*128 + t] = a1;
      sm[416 + l*128 + t] = a2;
    }
  }
}

// -------- weight pre-conversion f32 -> bf16, PRE-SWIZZLED chunk order -------
__device__ __forceinline__ uint4 cvt8(const float* __restrict__ p){
  float4 v0 = *(const float4*)p;
  float4 v1 = *(const float4*)(p + 4);
  uint4 o;
  o.x = pack2(v0.x, v0.y);
  o.y = pack2(v0.z, v0.w);
  o.z = pack2(v1.x, v1.y);
  o.w = pack2(v1.z, v1.w);
  return o;
}
// wsb: 16 matrices x 2048 chunks; chunk (r,c) stored at r*16 + (c ^ (r&15))
__global__ void k_wcvt(const float* __restrict__ lin1W, const float* __restrict__ gcnW,
                       const float* __restrict__ Ws, const float* __restrict__ Wn,
                       const float* __restrict__ ginW, const float* __restrict__ gatW,
                       u16* __restrict__ wsb)
{
  int i = blockIdx.x*256 + threadIdx.x;
  if (i >= 32768) return;
  int m = i >> 11;
  int j = i & 2047;
  int r = j >> 4, c = j & 15;
  const float* src;
  if (m == 0)       src = lin1W;
  else if (m < 4)   src = gcnW + (m-1)*16384;
  else if (m < 7)   src = Ws   + (m-4)*16384;
  else if (m < 10)  src = Wn   + (m-7)*16384;
  else if (m < 13)  src = ginW + (m-10)*16384;
  else              src = gatW + (m-13)*16384;
  int dj = r*16 + (c ^ (r & 15));
  *(uint4*)(wsb + ((size_t)m*2048 + dj)*8) = cvt8(src + r*HD + c*8);
}

// ---------------- CSR build (multi-block scan) ----------------
__global__ void k_count(const int* __restrict__ ei, int E, int* __restrict__ cnt){
  int e = blockIdx.x*256 + threadIdx.x;
  if (e < E) atomicAdd(&cnt[ei[E + e]], 1);
}

__global__ void k_scan1(const int* __restrict__ cnt, int Nn, int* __restrict__ bsum){
  __shared__ int red[256];
  int b = blockIdx.x, t = threadIdx.x;
  int base = b*1024 + t*4;
  int s = 0;
  #pragma unroll
  for (int k = 0; k < 4; k++){ int i = base + k; if (i < Nn) s += cnt[i]; }
  red[t] = s; __syncthreads();
  for (int off = 128; off; off >>= 1){
    if (t < off) red[t] += red[t + off];
    __syncthreads();
  }
  if (t == 0) bsum[b] = red[0];
}

__global__ void k_scan2(const int* __restrict__ bsum, int nb,
                        int* __restrict__ boffs, int* __restrict__ rowptr, int Nn){
  __shared__ int sc[1024];
  int t = threadIdx.x;
  int own = (t < nb) ? bsum[t] : 0;
  sc[t] = own;
  __syncthreads();
  for (int off = 1; off < 1024; off <<= 1){
    int add = (t >= off) ? sc[t - off] : 0;
    __syncthreads();
    sc[t] += add;
    __syncthreads();
  }
  if (t < nb) boffs[t] = sc[t] - own;
  if (t == 1023) rowptr[Nn] = sc[1023];
}

__global__ void k_scan3(const int* __restrict__ cnt, const int* __restrict__ boffs, int Nn,
                        int* __restrict__ rowptr, int* __restrict__ cursor,
                        float4* __restrict__ nd){
  __shared__ int red[256];
  int b = blockIdx.x, t = threadIdx.x;
  int base = b*1024 + t*4;
  int c[4]; int s = 0;
  #pragma unroll
  for (int k = 0; k < 4; k++){ int i = base + k; c[k] = (i < Nn) ? cnt[i] : 0; s += c[k]; }
  red[t] = s; __syncthreads();
  for (int off = 1; off < 256; off <<= 1){
    int add = (t >= off) ? red[t - off] : 0;
    __syncthreads();
    red[t] += add;
    __syncthreads();
  }
  int run = red[t] - s + boffs[b];
  #pragma unroll
  for (int k = 0; k < 4; k++){
    int i = base + k;
    if (i < Nn){
      rowptr[i] = run; cursor[i] = run;
      float f = (float)c[k];
      nd[i].z = c[k] > 0 ? 1.f/sqrtf(f) : 0.f;   // dis
      nd[i].w = 1.f/fmaxf(f, 1.f);               // dinv
      run += c[k];
    }
  }
}

__global__ void k_fill(const int* __restrict__ ei, int E,
                       int* __restrict__ cursor, int* __restrict__ csr){
  int e = blockIdx.x*256 + threadIdx.x;
  if (e < E){
    int sv = ei[e], dv = ei[E + e];
    int pos = atomicAdd(&cursor[dv], 1);
    csr[pos] = sv;
  }
}

// ---------------- per-node GAT scalars -> nd.x (s), nd.y (d) ----------------
__global__ __launch_bounds__(256)
void k_sd(const u16* __restrict__ X, const float* __restrict__ sm, int layer, int Nn,
          float4* __restrict__ nd)
{
  int wv = blockIdx.x*4 + (threadIdx.x >> 6);
  if (wv >= Nn) return;
  int lane = threadIdx.x & 63;
  u32 xv = *(const u32*)(X + (size_t)wv*HD + lane*2);
  float x0 = lo2f(xv), x1 = hi2f(xv);
  const float* wsv = sm + 32  + layer*128;
  const float* wdv = sm + 416 + layer*128;
  float ps = x0*wsv[2*lane] + x1*wsv[2*lane+1];
  float pd = x0*wdv[2*lane] + x1*wdv[2*lane+1];
  #pragma unroll
  for (int off = 32; off > 0; off >>= 1){
    ps += __shfl_xor(ps, off);
    pd += __shfl_xor(pd, off);
  }
  if (lane == 0) *(float2*)(&nd[wv]) = make_float2(ps, pd);
}

// ------- aggregation: wave/dst, 4 edge-groups x2 unroll, packed f32 math ----
// outputs Qb/Pb/Rb stored in SWIZZLED chunk order: node v chunk t -> t^(v&15)
__global__ __launch_bounds__(256)
void k_agg(const u16* __restrict__ X, const int* __restrict__ rowptr, const int* __restrict__ csr,
           const float4* __restrict__ nd, int Nn,
           u16* __restrict__ Qb, u16* __restrict__ Pb, u16* __restrict__ Rb,
           float* __restrict__ b0)
{
  int wv = blockIdx.x*4 + (threadIdx.x >> 6);
  if (wv >= Nn) return;
  int lane = threadIdx.x & 63;
  int g = lane >> 4, t = lane & 15;
  int beg = rowptr[wv], end = rowptr[wv+1];
  float4 ndw = nd[wv];
  float dval = ndw.y;
  // pass 1: exact segment max of leaky_relu(s[src]+d[v])
  float mloc = -3.4e38f;
  for (int e = beg + lane; e < end; e += 64){
    float s = nd[csr[e]].x + dval;
    float lg = s > 0.f ? s : 0.2f*s;
    mloc = fmaxf(mloc, lg);
  }
  #pragma unroll
  for (int off = 32; off > 0; off >>= 1) mloc = fmaxf(mloc, __shfl_xor(mloc, off));
  // pass 2: packed accumulate, 8 edges in flight per wave
  f32x2 p2[4], q2[4], r2[4];
  #pragma unroll
  for (int k = 0; k < 4; k++){ p2[k] = (f32x2){0.f,0.f}; q2[k] = (f32x2){0.f,0.f}; r2[k] = (f32x2){0.f,0.f}; }
  float z = 0.f, qd = 0.f;
  int e = beg + g;
  for (; e + 4 < end; e += 8){
    int sv0 = csr[e], sv1 = csr[e+4];
    float4 n0 = nd[sv0], n1 = nd[sv1];
    uint4 xv0 = *(const uint4*)(X + (size_t)sv0*HD + t*8);
    uint4 xv1 = *(const uint4*)(X + (size_t)sv1*HD + t*8);
    float s0 = n0.x + dval, s1 = n1.x + dval;
    float lg0 = s0 > 0.f ? s0 : 0.2f*s0;
    float lg1 = s1 > 0.f ? s1 : 0.2f*s1;
    float ew0 = __expf(lg0 - mloc), ew1 = __expf(lg1 - mloc);
    u32 a0[4] = {xv0.x, xv0.y, xv0.z, xv0.w};
    u32 a1[4] = {xv1.x, xv1.y, xv1.z, xv1.w};
    f32x2 d0 = {n0.z, n0.z}, d1 = {n1.z, n1.z};
    f32x2 e0 = {ew0, ew0},   e1v = {ew1, ew1};
    #pragma unroll
    for (int k = 0; k < 4; k++){
      f32x2 xf0 = {lo2f(a0[k]), hi2f(a0[k])};
      f32x2 xf1 = {lo2f(a1[k]), hi2f(a1[k])};
      p2[k] += xf0 + xf1;
      q2[k] = __builtin_elementwise_fma(xf0, d0, q2[k]);
      q2[k] = __builtin_elementwise_fma(xf1, d1, q2[k]);
      r2[k] = __builtin_elementwise_fma(xf0, e0, r2[k]);
      r2[k] = __builtin_elementwise_fma(xf1, e1v, r2[k]);
    }
    z += ew0 + ew1; qd += n0.z + n1.z;
  }
  if (e < end){
    int sv = csr[e];
    float4 n0 = nd[sv];
    uint4 xv = *(const uint4*)(X + (size_t)sv*HD + t*8);
    float s = n0.x + dval;
    float lg = s > 0.f ? s : 0.2f*s;
    float ew = __expf(lg - mloc);
    u32 a0[4] = {xv.x, xv.y, xv.z, xv.w};
    f32x2 d0 = {n0.z, n0.z}, e0 = {ew, ew};
    #pragma unroll
    for (int k = 0; k < 4; k++){
      f32x2 xf = {lo2f(a0[k]), hi2f(a0[k])};
      p2[k] += xf;
      q2[k] = __builtin_elementwise_fma(xf, d0, q2[k]);
      r2[k] = __builtin_elementwise_fma(xf, e0, r2[k]);
    }
    z += ew; qd += n0.z;
  }
  // cross-group reduce (lane bits 4,5)
  #pragma unroll
  for (int off = 16; off <= 32; off <<= 1){
    #pragma unroll
    for (int k = 0; k < 4; k++){
      p2[k].x += __shfl_xor(p2[k].x, off); p2[k].y += __shfl_xor(p2[k].y, off);
      q2[k].x += __shfl_xor(q2[k].x, off); q2[k].y += __shfl_xor(q2[k].y, off);
      r2[k].x += __shfl_xor(r2[k].x, off); r2[k].y += __shfl_xor(r2[k].y, off);
    }
    z  += __shfl_xor(z, off);
    qd += __shfl_xor(qd, off);
  }
  if (g == 0){
    float disv = ndw.z;
    float zinv = 1.f/(z + 1e-16f);
    int tch = t ^ (wv & 15);
    size_t o = (size_t)wv*HD + tch*8;
    uint4 qo, po, ro;
    qo.x = pack2(disv*q2[0].x, disv*q2[0].y); qo.y = pack2(disv*q2[1].x, disv*q2[1].y);
    qo.z = pack2(disv*q2[2].x, disv*q2[2].y); qo.w = pack2(disv*q2[3].x, disv*q2[3].y);
    po.x = pack2(p2[0].x, p2[0].y); po.y = pack2(p2[1].x, p2[1].y);
    po.z = pack2(p2[2].x, p2[2].y); po.w = pack2(p2[3].x, p2[3].y);
    ro.x = pack2(zinv*r2[0].x, zinv*r2[0].y); ro.y = pack2(zinv*r2[1].x, zinv*r2[1].y);
    ro.z = pack2(zinv*r2[2].x, zinv*r2[2].y); ro.w = pack2(zinv*r2[3].x, zinv*r2[3].y);
    *(uint4*)(Qb + o) = qo;
    *(uint4*)(Pb + o) = po;
    *(uint4*)(Rb + o) = ro;
    if (t == 0) b0[wv] = disv*qd;
  }
}

// ---------------- MFMA helpers, M=64 tile ----------------
// async linear copy of pre-swizzled source (B weights; swizzled A buffers)
__device__ __forceinline__ void stageB_async(u16* lds, const u16* __restrict__ w, int tid){
  int lane = tid & 63, wave = tid >> 6;
  #pragma unroll
  for (int i = 0; i < 8; i++){
    int cb = wave*64 + 256*i;
    async16(w + (size_t)(cb + lane)*8, lds + (size_t)cb*8);
  }
}
__device__ __forceinline__ void stageA64_async(u16* lds, const u16* __restrict__ src,
                                               int mbase, int Nn, int tid){
  int lane = tid & 63, wave = tid >> 6;
  #pragma unroll
  for (int i = 0; i < 4; i++){
    int cb = wave*64 + 256*i;
    int gr = mbase + ((cb + lane) >> 4);
    if (gr < Nn)
      async16(src + ((size_t)mbase*16 + cb + lane)*8, lds + (size_t)cb*8);
  }
}
// X is LINEAR layout: XOR-write staging
__device__ __forceinline__ void stageA64(u16* lds, const u16* __restrict__ src,
                                         int mbase, int Nn, int tid){
  #pragma unroll
  for (int i = 0; i < 4; i++){
    int chunk = tid + 256*i;
    int r = chunk >> 4;
    int c = chunk & 15;
    uint4 v = {0u,0u,0u,0u};
    int gr = mbase + r;
    if (gr < Nn) v = *(const uint4*)(src + (size_t)gr*HD + c*8);
    *(uint4*)(lds + (r*16 + (c ^ (r & 15)))*8) = v;
  }
}
// Pb (swizzled source) with per-row scale -> linear chunk copy + scale
__device__ __forceinline__ void stageA64_scale(u16* lds, const u16* __restrict__ src,
                                               const float4* __restrict__ nd,
                                               int mbase, int Nn, int tid){
  #pragma unroll
  for (int i = 0; i < 4; i++){
    int chunk = tid + 256*i;
    int gr = mbase + (chunk >> 4);
    uint4 v = {0u,0u,0u,0u};
    if (gr < Nn){
      uint4 raw = *(const uint4*)(src + ((size_t)mbase*16 + chunk)*8);
      float s = nd[gr].w;
      v.x = pack2(lo2f(raw.x)*s, hi2f(raw.x)*s);
      v.y = pack2(lo2f(raw.y)*s, hi2f(raw.y)*s);
      v.z = pack2(lo2f(raw.z)*s, hi2f(raw.z)*s);
      v.w = pack2(lo2f(raw.w)*s, hi2f(raw.w)*s);
    }
    *(uint4*)(lds + (size_t)chunk*8) = v;
  }
}
// GIN tile: e1*X(linear) + Pb(swizzled)
__device__ __forceinline__ void stageA64_gin(u16* lds, const u16* __restrict__ X,
                                             const u16* __restrict__ Pb, float e1,
                                             int mbase, int Nn, int tid){
  #pragma unroll
  for (int i = 0; i < 4; i++){
    int chunk = tid + 256*i;
    int r = chunk >> 4;
    int c = (chunk & 15) ^ (r & 15);
    int gr = mbase + r;
    uint4 v = {0u,0u,0u,0u};
    if (gr < Nn){
      uint4 xr = *(const uint4*)(X  + (size_t)gr*HD + c*8);
      uint4 pr = *(const uint4*)(Pb + ((size_t)mbase*16 + chunk)*8);
      v.x = pack2(fmaf(e1, lo2f(xr.x), lo2f(pr.x)), fmaf(e1, hi2f(xr.x), hi2f(pr.x)));
      v.y = pack2(fmaf(e1, lo2f(xr.y), lo2f(pr.y)), fmaf(e1, hi2f(xr.y), hi2f(pr.y)));
      v.z = pack2(fmaf(e1, lo2f(xr.z), lo2f(pr.z)), fmaf(e1, hi2f(xr.z), hi2f(pr.z)));
      v.w = pack2(fmaf(e1, lo2f(xr.w), lo2f(pr.w)), fmaf(e1, hi2f(xr.w), hi2f(pr.w)));
    }
    *(uint4*)(lds + (size_t)chunk*8) = v;
  }
}
__device__ __forceinline__ void stageA64_f32(u16* lds, const float* __restrict__ src,
                                             int mbase, int Nn, int tid){
  #pragma unroll
  for (int i = 0; i < 4; i++){
    int chunk = tid + 256*i;
    int r = chunk >> 4;
    int c = chunk & 15;
    uint4 v = {0u,0u,0u,0u};
    int gr = mbase + r;
    if (gr < Nn) v = cvt8(src + (size_t)gr*HD + c*8);
    *(uint4*)(lds + (r*16 + (c ^ (r & 15)))*8) = v;
  }
}
__device__ __forceinline__ void mfma_tile64(const u16* Als, const u16* Bls,
                                            int m0, int lane, f32x4 acc[8]){
  int quad = lane >> 4, lr = lane & 15;
  #pragma unroll
  for (int ks = 0; ks < 4; ks++){
    int q = ks*4 + quad;
    short8 a, b[8];
    int row = m0 + lr;
    a = *(const short8*)(Als + (row*16 + (q ^ lr))*8);
    #pragma unroll
    for (int ct = 0; ct < 8; ct++){
      int brow = ct*16 + lr;
      b[ct] = *(const short8*)(Bls + (brow*16 + (q ^ lr))*8);
    }
    #pragma unroll
    for (int ct = 0; ct < 8; ct++)
      acc[ct] = __builtin_amdgcn_mfma_f32_16x16x32_bf16(a, b[ct], acc[ct], 0, 0, 0);
  }
}

// ---------------- lin1: xh(bf16) = f32(x) @ W^T + b  (M=64) ----------------
__global__ __launch_bounds__(256,3)
void k_gemm1(const float* __restrict__ A, const u16* __restrict__ Wb, const float* __restrict__ bias,
             int Nn, u16* __restrict__ out)
{
  __shared__ __align__(16) u16 Als[64*128];
  __shared__ __align__(16) u16 Bls[128*128];
  int tid = threadIdx.x;
  int lane = tid & 63, wave = tid >> 6;
  int m0 = wave*16, mbase = blockIdx.x*64;
  int quad = lane >> 4, lr = lane & 15;
  f32x4 acc[8];
  #pragma unroll
  for (int ct=0;ct<8;ct++) acc[ct] = (f32x4){0.f,0.f,0.f,0.f};
  stageB_async(Bls, Wb, tid);
  stageA64_f32(Als, A, mbase, Nn, tid);
  __syncthreads();
  mfma_tile64(Als, Bls, m0, lane, acc);
  float bcol[8];
  #pragma unroll
  for (int ct=0;ct<8;ct++) bcol[ct] = bias[ct*16+lr];
  #pragma unroll
  for (int ct=0;ct<8;ct++)
    #pragma unroll
    for (int r=0;r<4;r++){
      int grow = mbase + m0 + quad*4 + r;
      if (grow < Nn) out[(size_t)grow*HD + ct*16+lr] = f2b(sane(acc[ct][r] + bcol[ct]));
    }
}

// ---------------- fused layer (GEMM-only, M=64): 5 GEMMs + elu mix ----------
__global__ __launch_bounds__(256,3)
void k_layer3(const u16* __restrict__ X, const u16* __restrict__ Qb,
              const u16* __restrict__ Pb, const u16* __restrict__ Rb,
              const float4* __restrict__ nd, const float* __restrict__ b0,
              const u16* __restrict__ wsb,
              const float* __restrict__ gcnB, const float* __restrict__ ginB,
              const float* __restrict__ sm, int layer, int Nn, u16* __restrict__ out)
{
  __shared__ __align__(16) u16 At[64*128];
  __shared__ __align__(16) u16 Bt[128*128];
  int tid = threadIdx.x;
  int lane = tid & 63, wave = tid >> 6;
  int m0 = wave*16, mbase = blockIdx.x*64;
  int quad = lane >> 4, lr = lane & 15;
  float w0 = sm[layer*4+0], w1 = sm[layer*4+1], w2 = sm[layer*4+2], w3 = sm[layer*4+3];
  float e1 = sm[17 + layer];
  const u16* gcnWb = wsb + (size_t)(1  + layer)*16384;
  const u16* WsWb  = wsb + (size_t)(4  + layer)*16384;
  const u16* WnWb  = wsb + (size_t)(7  + layer)*16384;
  const u16* ginWb = wsb + (size_t)(10 + layer)*16384;
  const u16* gatWb = wsb + (size_t)(13 + layer)*16384;

  f32x4 mix[8];
  f32x4 acc[8];
  float b0r[4];
  #pragma unroll
  for (int r=0;r<4;r++){
    int grow = mbase + m0 + quad*4 + r;
    b0r[r] = (grow < Nn) ? b0[grow] : 0.f;
  }

  // ---- op0: GCN (Qb swizzled -> async) ----
  stageB_async(Bt, gcnWb, tid);
  stageA64_async(At, Qb, mbase, Nn, tid);
  __syncthreads();
  #pragma unroll
  for (int ct=0;ct<8;ct++) acc[ct] = (f32x4){0.f,0.f,0.f,0.f};
  mfma_tile64(At, Bt, m0, lane, acc);
  {
    float gb[8];
    #pragma unroll
    for (int ct=0;ct<8;ct++) gb[ct] = gcnB[layer*HD + ct*16+lr];
    #pragma unroll
    for (int ct=0;ct<8;ct++)
      #pragma unroll
      for (int r=0;r<4;r++)
        mix[ct][r] = w0 * eluf(acc[ct][r] + b0r[r]*gb[ct]);
  }
  __syncthreads();

  // ---- op1: SAGE self (X linear) ----
  stageB_async(Bt, WsWb, tid);
  stageA64(At, X, mbase, Nn, tid);
  __syncthreads();
  #pragma unroll
  for (int ct=0;ct<8;ct++) acc[ct] = (f32x4){0.f,0.f,0.f,0.f};
  mfma_tile64(At, Bt, m0, lane, acc);
  __syncthreads();
  // ---- SAGE neighbor (Pb swizzled, row-scaled at staging) ----
  stageB_async(Bt, WnWb, tid);
  stageA64_scale(At, Pb, nd, mbase, Nn, tid);
  __syncthreads();
  mfma_tile64(At, Bt, m0, lane, acc);
  #pragma unroll
  for (int ct=0;ct<8;ct++)
    #pragma unroll
    for (int r=0;r<4;r++)
      mix[ct][r] += w1 * eluf(acc[ct][r]);
  __syncthreads();

  // ---- op2: GIN ----
  stageB_async(Bt, ginWb, tid);
  stageA64_gin(At, X, Pb, e1, mbase, Nn, tid);
  __syncthreads();
  #pragma unroll
  for (int ct=0;ct<8;ct++) acc[ct] = (f32x4){0.f,0.f,0.f,0.f};
  mfma_tile64(At, Bt, m0, lane, acc);
  {
    float gib[8];
    #pragma unroll
    for (int ct=0;ct<8;ct++) gib[ct] = ginB[layer*HD + ct*16+lr];
    #pragma unroll
    for (int ct=0;ct<8;ct++)
      #pragma unroll
      for (int r=0;r<4;r++)
        mix[ct][r] += w2 * eluf(acc[ct][r] + gib[ct]);
  }
  __syncthreads();

  // ---- op3: GAT (Rb swizzled -> async) ----
  stageB_async(Bt, gatWb, tid);
  stageA64_async(At, Rb, mbase, Nn, tid);
  __syncthreads();
  #pragma unroll
  for (int ct=0;ct<8;ct++) acc[ct] = (f32x4){0.f,0.f,0.f,0.f};
  mfma_tile64(At, Bt, m0, lane, acc);
  #pragma unroll
  for (int ct=0;ct<8;ct++)
    #pragma unroll
    for (int r=0;r<4;r++)
      mix[ct][r] += w3 * eluf(acc[ct][r]);

  // ---- store (linear bf16) ----
  #pragma unroll
  for (int ct=0;ct<8;ct++)
    #pragma unroll
    for (int r=0;r<4;r++){
      int grow = mbase + m0 + quad*4 + r;
      if (grow < Nn) out[(size_t)grow*HD + ct*16+lr] = f2b(sane(mix[ct][r]));
    }
}

// ------- classifier with fused skip/layer-agg ----------
__global__ __launch_bounds__(256)
void k_nc(const u16* __restrict__ X1, const u16* __restrict__ X2, const u16* __restrict__ X3,
          const float* __restrict__ W, const float* __restrict__ bias,
          const float* __restrict__ sm, int Nn, float* __restrict__ out)
{
  __shared__ __align__(16) u16 xs[32*136];
  __shared__ __align__(16) float wn[40*132];
  __shared__ float bs[40];
  int t = threadIdx.x;
  int nb = blockIdx.x*32;
  float c1 = sm[12], c2 = sm[13], la0 = sm[14], la1 = sm[15], la2 = sm[16];
  #pragma unroll
  for (int i = 0; i < 2; i++){
    int chunk = t + 256*i;
    int r = chunk >> 4, c = chunk & 15;
    uint4 v = {0u,0u,0u,0u};
    int gr = nb + r;
    if (gr < Nn){
      size_t o = (size_t)gr*HD + c*8;
      uint4 u1 = *(const uint4*)(X1 + o);
      uint4 u2 = *(const uint4*)(X2 + o);
      uint4 u3 = *(const uint4*)(X3 + o);
      u32* u1p = (u32*)&u1; u32* u2p = (u32*)&u2; u32* u3p = (u32*)&u3; u32* vp = (u32*)&v;
      #pragma unroll
      for (int k = 0; k < 4; k++){
        float o0, o1;
        {
          float a1 = lo2f(u1p[k]), a2 = lo2f(u2p[k]), a3 = lo2f(u3p[k]);
          float t0 = a3, t1 = c1*a1, t2 = c2*a2;
          float smm = t0 + t1 + t2;
          float mx = fmaxf(fmaxf(t0,t1),t2);
          o0 = la0*reluf(mx) + la1*reluf(smm*(1.f/3.f)) + la2*reluf(smm);
        }
        {
          float a1 = hi2f(u1p[k]), a2 = hi2f(u2p[k]), a3 = hi2f(u3p[k]);
          float t0 = a3, t1 = c1*a1, t2 = c2*a2;
          float smm = t0 + t1 + t2;
          float mx = fmaxf(fmaxf(t0,t1),t2);
          o1 = la0*reluf(mx) + la1*reluf(smm*(1.f/3.f)) + la2*reluf(smm);
        }
        vp[k] = pack2(sane(o0), sane(o1));
      }
    }
    *(uint4*)(xs + r*136 + c*8) = v;
  }
  #pragma unroll
  for (int i = 0; i < 5; i++){
    int chunk = t + 256*i;
    int r = chunk >> 5, c = chunk & 31;
    *(float4*)(wn + r*132 + c*4) = *(const float4*)(W + r*HD + c*4);
  }
  if (t < 40) bs[t] = bias[t];
  __syncthreads();
  int nl = t >> 3, cg = t & 7;
  float acc[5];
  #pragma unroll
  for (int j = 0; j < 5; j++) acc[j] = bs[cg + 8*j];
  for (int k = 0; k < 128; k++){
    float xv = b2f(xs[nl*136 + k]);
    #pragma unroll
    for (int j = 0; j < 5; j++)
      acc[j] = fmaf(xv, wn[(cg + 8*j)*132 + k], acc[j]);
  }
  int gr = nb + nl;
  if (gr < Nn){
    #pragma unroll
    for (int j = 0; j < 5; j++)
      out[(size_t)gr*40 + cg + 8*j] = sane(acc[j]);
  }
}

// ---------------- host ----------------
extern "C" void kernel_launch(void* const* d_in, const int* in_sizes, int n_in,
                              void* d_out, int out_size, void* d_ws, size_t ws_size,
                              hipStream_t stream)
{
  (void)n_in; (void)out_size; (void)ws_size;
  const int N = in_sizes[0] / HD;
  const int E = in_sizes[1] / 2;
  const float* x      = (const float*)d_in[0];
  const int*   ei     = (const int*)d_in[1];
  const float* na_a   = (const float*)d_in[2];
  const float* sc_a   = (const float*)d_in[3];
  const float* la_a   = (const float*)d_in[4];
  const float* lin1W  = (const float*)d_in[5];
  const float* lin1b  = (const float*)d_in[6];
  const float* gcnW   = (const float*)d_in[7];
  const float* gcnB   = (const float*)d_in[8];
  const float* sageWs = (const float*)d_in[9];
  const float* sageWn = (const float*)d_in[10];
  const float* ginW   = (const float*)d_in[11];
  const float* ginB   = (const float*)d_in[12];
  const float* ginE   = (const float*)d_in[13];
  const float* gatW   = (const float*)d_in[14];
  const float* gatAs  = (const float*)d_in[15];
  const float* gatAd  = (const float*)d_in[16];
  const float* ncW    = (const float*)d_in[17];
  const float* ncB    = (const float*)d_in[18];

  char* base = (char*)d_ws;
  size_t off = 0;
  auto alloc = [&](size_t b) -> void* {
    void* p = base + off;
    off += (b + 255) & ~(size_t)255;
    return p;
  };
  const int NB = (N + 1023) / 1024;
  float*  smalls = (float*)alloc(4096);
  int*    cnt    = (int*)alloc((size_t)N*4);
  int*    rowptr = (int*)alloc(((size_t)N+1)*4);
  int*    cursor = (int*)alloc((size_t)N*4);
  int*    bsum   = (int*)alloc(4096);
  int*    boffs  = (int*)alloc(4096);
  float4* nd     = (float4*)alloc((size_t)N*16);   // (s, d, dis, dinv)
  float*  b0     = (float*)alloc((size_t)N*4);
  int*    csr    = (int*)alloc((size_t)E*4);
  u16*    wsb    = (u16*)alloc((size_t)16*16384*2);
  u16*    xh     = (u16*)alloc((size_t)N*HD*2);   // h after lin1; reused as x3
  u16*    x1     = (u16*)alloc((size_t)N*HD*2);
  u16*    x2     = (u16*)alloc((size_t)N*HD*2);
  u16*    Qb     = (u16*)alloc((size_t)N*HD*2);
  u16*    Pb     = (u16*)alloc((size_t)N*HD*2);
  u16*    Rb     = (u16*)alloc((size_t)N*HD*2);

  hipMemsetAsync(cnt, 0, (size_t)N*4, stream);
  k_small<<<1,128,0,stream>>>(na_a, sc_a, la_a, gatW, gatAs, gatAd, ginE, smalls);
  k_wcvt<<<128,256,0,stream>>>(lin1W, gcnW, sageWs, sageWn, ginW, gatW, wsb);
  int ebl = (E + 255)/256;
  k_count<<<ebl,256,0,stream>>>(ei, E, cnt);
  k_scan1<<<NB,256,0,stream>>>(cnt, N, bsum);
  k_scan2<<<1,1024,0,stream>>>(bsum, NB, boffs, rowptr, N);
  k_scan3<<<NB,256,0,stream>>>(cnt, boffs, N, rowptr, cursor, nd);
  k_fill<<<ebl,256,0,stream>>>(ei, E, cursor, csr);
  int gbl64 = (N + 63)/64;
  k_gemm1<<<gbl64,256,0,stream>>>(x, wsb, lin1b, N, xh);
  const u16* xc = xh;
  u16* outs[3] = {x1, x2, xh};    // x3 reuses xh (dead after layer 0)
  int wbl = (N + 3)/4;
  for (int l = 0; l < 3; l++){
    k_sd<<<wbl,256,0,stream>>>(xc, smalls, l, N, nd);
    k_agg<<<wbl,256,0,stream>>>(xc, rowptr, csr, nd, N, Qb, Pb, Rb, b0);
    k_layer3<<<gbl64,256,0,stream>>>(xc, Qb, Pb, Rb, nd, b0, wsb,
                                     gcnB, ginB, smalls, l, N, outs[l]);
    xc = outs[l];
  }
  int ncbl = (N + 31)/32;
  k_nc<<<ncbl,256,0,stream>>>(x1, x2, xh, ncW, ncB, smalls, N, (float*)d_out);
}

// Round 8
// 521.133 us; speedup vs baseline: 8.5209x; 1.1098x over previous
//
#include <hip/hip_runtime.h>

typedef unsigned short u16;
typedef unsigned int u32;
typedef __attribute__((ext_vector_type(8))) short short8;
typedef __attribute__((ext_vector_type(4))) float f32x4;
typedef __attribute__((ext_vector_type(2))) float f32x2;

#define HD 128

__device__ inline float b2f(u16 u){ u32 v = ((u32)u) << 16; return __uint_as_float(v); }
__device__ inline u16 f2b(float f){
  u32 u = __float_as_uint(f);
  u32 r = (u + 0x7fffu + ((u >> 16) & 1u)) >> 16;
  return (u16)r;
}
__device__ inline u32 pack2(float a, float b){ return (u32)f2b(a) | ((u32)f2b(b) << 16); }
__device__ inline float lo2f(u32 w){ return b2f((u16)(w & 0xffff)); }
__device__ inline float hi2f(u32 w){ return b2f((u16)(w >> 16)); }
__device__ inline float eluf(float x){ return x > 0.f ? x : __expf(x) - 1.f; }
__device__ inline float reluf(float x){ return x > 0.f ? x : 0.f; }
__device__ inline float sane(float x){
  if (!(x == x)) return 0.f;
  return fminf(fmaxf(x, -1e30f), 1e30f);
}
// monotone float<->u32 encoding for atomicMax on signed floats
__device__ inline u32 fenc(float f){ u32 u = __float_as_uint(f); return (u & 0x80000000u) ? ~u : (u | 0x80000000u); }
__device__ inline float fdec(u32 u){ return __uint_as_float((u & 0x80000000u) ? (u & 0x7fffffffu) : ~u); }
// async 16B global->LDS (lds base wave-uniform; lane i lands at base + i*16)
__device__ __forceinline__ void async16(const u16* g, u16* l){
  __builtin_amdgcn_global_load_lds((const __attribute__((address_space(1))) void*)g,
                                   (__attribute__((address_space(3))) void*)l, 16, 0, 0);
}

// ---------------- small precompute ----------------
__global__ void k_small(const float* __restrict__ na_a, const float* __restrict__ sc_a,
                        const float* __restrict__ la_a, const float* __restrict__ gatW,
                        const float* __restrict__ gat_as, const float* __restrict__ gat_ad,
                        const float* __restrict__ gin_eps, float* __restrict__ sm,
                        u32* __restrict__ maxs)
{
  int t = threadIdx.x;
  if (t < 3) maxs[t] = 0u;   // encoded -inf floor
  if (t == 0){
    for (int l = 0; l < 3; l++){
      float a[4]; float mx = -1e30f;
      for (int i = 0; i < 4; i++){ a[i] = na_a[l*4+i]; mx = fmaxf(mx, a[i]); }
      float ssum = 0.f;
      for (int i = 0; i < 4; i++){ a[i] = __expf(a[i]-mx); ssum += a[i]; }
      for (int i = 0; i < 4; i++) sm[l*4+i] = a[i]/ssum;
    }
    for (int r = 0; r < 2; r++){
      float a0 = sc_a[r*2], a1 = sc_a[r*2+1];
      float mx = fmaxf(a0,a1);
      float e0 = __expf(a0-mx), e1 = __expf(a1-mx);
      sm[12+r] = e1/(e0+e1);
    }
    {
      float a0=la_a[0], a1=la_a[1], a2=la_a[2];
      float mx = fmaxf(fmaxf(a0,a1),a2);
      float e0=__expf(a0-mx), e1=__expf(a1-mx), e2=__expf(a2-mx);
      float ssum = e0+e1+e2;
      sm[14]=e0/ssum; sm[15]=e1/ssum; sm[16]=e2/ssum;
    }
    for (int l=0;l<3;l++) sm[17+l] = 1.f + gin_eps[l];
  }
  if (t < 128){
    for (int l=0;l<3;l++){
      float a1=0.f, a2=0.f;
      for (int k=0;k<128;k++){
        float wv = gatW[l*16384 + k*128 + t];
        a1 = fmaf(wv, gat_as[l*128+k], a1);
        a2 = fmaf(wv, gat_ad[l*128+k], a2);
      }
      sm[32  + l*128 + t] = a1;
      sm[416 + l*128 + t] = a2;
    }
  }
}

// -------- weight pre-conversion f32 -> bf16, PRE-SWIZZLED chunk order -------
__device__ __forceinline__ uint4 cvt8(const float* __restrict__ p){
  float4 v0 = *(const float4*)p;
  float4 v1 = *(const float4*)(p + 4);
  uint4 o;
  o.x = pack2(v0.x, v0.y);
  o.y = pack2(v0.z, v0.w);
  o.z = pack2(v1.x, v1.y);
  o.w = pack2(v1.z, v1.w);
  return o;
}
__global__ void k_wcvt(const float* __restrict__ lin1W, const float* __restrict__ gcnW,
                       const float* __restrict__ Ws, const float* __restrict__ Wn,
                       const float* __restrict__ ginW, const float* __restrict__ gatW,
                       u16* __restrict__ wsb)
{
  int i = blockIdx.x*256 + threadIdx.x;
  if (i >= 32768) return;
  int m = i >> 11;
  int j = i & 2047;
  int r = j >> 4, c = j & 15;
  const float* src;
  if (m == 0)       src = lin1W;
  else if (m < 4)   src = gcnW + (m-1)*16384;
  else if (m < 7)   src = Ws   + (m-4)*16384;
  else if (m < 10)  src = Wn   + (m-7)*16384;
  else if (m < 13)  src = ginW + (m-10)*16384;
  else              src = gatW + (m-13)*16384;
  int dj = r*16 + (c ^ (r & 15));
  *(uint4*)(wsb + ((size_t)m*2048 + dj)*8) = cvt8(src + r*HD + c*8);
}

// ---------------- CSR build (multi-block scan) ----------------
__global__ void k_count(const int* __restrict__ ei, int E, int* __restrict__ cnt){
  int e = blockIdx.x*256 + threadIdx.x;
  if (e < E) atomicAdd(&cnt[ei[E + e]], 1);
}

__global__ void k_scan1(const int* __restrict__ cnt, int Nn, int* __restrict__ bsum){
  __shared__ int red[256];
  int b = blockIdx.x, t = threadIdx.x;
  int base = b*1024 + t*4;
  int s = 0;
  #pragma unroll
  for (int k = 0; k < 4; k++){ int i = base + k; if (i < Nn) s += cnt[i]; }
  red[t] = s; __syncthreads();
  for (int off = 128; off; off >>= 1){
    if (t < off) red[t] += red[t + off];
    __syncthreads();
  }
  if (t == 0) bsum[b] = red[0];
}

__global__ void k_scan2(const int* __restrict__ bsum, int nb,
                        int* __restrict__ boffs, int* __restrict__ rowptr, int Nn){
  __shared__ int sc[1024];
  int t = threadIdx.x;
  int own = (t < nb) ? bsum[t] : 0;
  sc[t] = own;
  __syncthreads();
  for (int off = 1; off < 1024; off <<= 1){
    int add = (t >= off) ? sc[t - off] : 0;
    __syncthreads();
    sc[t] += add;
    __syncthreads();
  }
  if (t < nb) boffs[t] = sc[t] - own;
  if (t == 1023) rowptr[Nn] = sc[1023];
}

__global__ void k_scan3(const int* __restrict__ cnt, const int* __restrict__ boffs, int Nn,
                        int* __restrict__ rowptr, int* __restrict__ cursor,
                        float4* __restrict__ nd){
  __shared__ int red[256];
  int b = blockIdx.x, t = threadIdx.x;
  int base = b*1024 + t*4;
  int c[4]; int s = 0;
  #pragma unroll
  for (int k = 0; k < 4; k++){ int i = base + k; c[k] = (i < Nn) ? cnt[i] : 0; s += c[k]; }
  red[t] = s; __syncthreads();
  for (int off = 1; off < 256; off <<= 1){
    int add = (t >= off) ? red[t - off] : 0;
    __syncthreads();
    red[t] += add;
    __syncthreads();
  }
  int run = red[t] - s + boffs[b];
  #pragma unroll
  for (int k = 0; k < 4; k++){
    int i = base + k;
    if (i < Nn){
      rowptr[i] = run; cursor[i] = run;
      float f = (float)c[k];
      nd[i].z = c[k] > 0 ? 1.f/sqrtf(f) : 0.f;   // dis
      nd[i].w = 1.f/fmaxf(f, 1.f);               // dinv
      run += c[k];
    }
  }
}

__global__ void k_fill(const int* __restrict__ ei, int E,
                       int* __restrict__ cursor, int* __restrict__ csr){
  int e = blockIdx.x*256 + threadIdx.x;
  if (e < E){
    int sv = ei[e], dv = ei[E + e];
    int pos = atomicAdd(&cursor[dv], 1);
    csr[pos] = sv;
  }
}

// ------- aggregation: wave/dst, single pass (global softmax bound) ----------
// X swizzled; outputs Qb/Pm/Gb/Rb swizzled: node v logical chunk t -> t^(v&15)
__global__ __launch_bounds__(256)
void k_agg(const u16* __restrict__ X, const int* __restrict__ rowptr, const int* __restrict__ csr,
           const float4* __restrict__ nd, const float* __restrict__ sm,
           const u32* __restrict__ maxs, int layer, int Nn,
           u16* __restrict__ Qb, u16* __restrict__ Pm, u16* __restrict__ Gb, u16* __restrict__ Rb,
           float* __restrict__ b0)
{
  int wv = blockIdx.x*4 + (threadIdx.x >> 6);
  if (wv >= Nn) return;
  int lane = threadIdx.x & 63;
  int g = lane >> 4, t = lane & 15;
  int beg = rowptr[wv], end = rowptr[wv+1];
  float4 ndw = nd[wv];
  float dval = ndw.y;
  float bnd = fdec(maxs[layer]) + dval;        // >= all s[src]+d
  float mloc = bnd > 0.f ? bnd : 0.2f*bnd;     // leaky monotone -> valid bound
  f32x2 p2[4], q2[4], r2[4];
  #pragma unroll
  for (int k = 0; k < 4; k++){ p2[k] = (f32x2){0.f,0.f}; q2[k] = (f32x2){0.f,0.f}; r2[k] = (f32x2){0.f,0.f}; }
  float z = 0.f, qd = 0.f;
  int e = beg + g;
  for (; e + 4 < end; e += 8){
    int sv0 = csr[e], sv1 = csr[e+4];
    float4 n0 = nd[sv0], n1 = nd[sv1];
    uint4 xv0 = *(const uint4*)(X + (size_t)sv0*HD + (t ^ (sv0 & 15))*8);
    uint4 xv1 = *(const uint4*)(X + (size_t)sv1*HD + (t ^ (sv1 & 15))*8);
    float s0 = n0.x + dval, s1 = n1.x + dval;
    float lg0 = s0 > 0.f ? s0 : 0.2f*s0;
    float lg1 = s1 > 0.f ? s1 : 0.2f*s1;
    float ew0 = __expf(lg0 - mloc), ew1 = __expf(lg1 - mloc);
    u32 a0[4] = {xv0.x, xv0.y, xv0.z, xv0.w};
    u32 a1[4] = {xv1.x, xv1.y, xv1.z, xv1.w};
    f32x2 d0 = {n0.z, n0.z}, d1 = {n1.z, n1.z};
    f32x2 e0 = {ew0, ew0},   e1v = {ew1, ew1};
    #pragma unroll
    for (int k = 0; k < 4; k++){
      f32x2 xf0 = {lo2f(a0[k]), hi2f(a0[k])};
      f32x2 xf1 = {lo2f(a1[k]), hi2f(a1[k])};
      p2[k] += xf0 + xf1;
      q2[k] = __builtin_elementwise_fma(xf0, d0, q2[k]);
      q2[k] = __builtin_elementwise_fma(xf1, d1, q2[k]);
      r2[k] = __builtin_elementwise_fma(xf0, e0, r2[k]);
      r2[k] = __builtin_elementwise_fma(xf1, e1v, r2[k]);
    }
    z += ew0 + ew1; qd += n0.z + n1.z;
  }
  if (e < end){
    int sv = csr[e];
    float4 n0 = nd[sv];
    uint4 xv = *(const uint4*)(X + (size_t)sv*HD + (t ^ (sv & 15))*8);
    float s = n0.x + dval;
    float lg = s > 0.f ? s : 0.2f*s;
    float ew = __expf(lg - mloc);
    u32 a0[4] = {xv.x, xv.y, xv.z, xv.w};
    f32x2 d0 = {n0.z, n0.z}, e0 = {ew, ew};
    #pragma unroll
    for (int k = 0; k < 4; k++){
      f32x2 xf = {lo2f(a0[k]), hi2f(a0[k])};
      p2[k] += xf;
      q2[k] = __builtin_elementwise_fma(xf, d0, q2[k]);
      r2[k] = __builtin_elementwise_fma(xf, e0, r2[k]);
    }
    z += ew; qd += n0.z;
  }
  // cross-group reduce (lane bits 4,5)
  #pragma unroll
  for (int off = 16; off <= 32; off <<= 1){
    #pragma unroll
    for (int k = 0; k < 4; k++){
      p2[k].x += __shfl_xor(p2[k].x, off); p2[k].y += __shfl_xor(p2[k].y, off);
      q2[k].x += __shfl_xor(q2[k].x, off); q2[k].y += __shfl_xor(q2[k].y, off);
      r2[k].x += __shfl_xor(r2[k].x, off); r2[k].y += __shfl_xor(r2[k].y, off);
    }
    z  += __shfl_xor(z, off);
    qd += __shfl_xor(qd, off);
  }
  if (g == 0){
    float disv = ndw.z, dinvv = ndw.w;
    float zinv = 1.f/(z + 1e-16f);
    float e1 = sm[17 + layer];
    int tch = t ^ (wv & 15);
    size_t o = (size_t)wv*HD + tch*8;
    uint4 xo = *(const uint4*)(X + o);   // own row, same swizzled chunk
    u32 ax[4] = {xo.x, xo.y, xo.z, xo.w};
    uint4 qo, po, go, ro;
    u32* qp = (u32*)&qo; u32* pp = (u32*)&po; u32* gp = (u32*)&go; u32* rp = (u32*)&ro;
    #pragma unroll
    for (int k = 0; k < 4; k++){
      float x0 = lo2f(ax[k]), x1 = hi2f(ax[k]);
      qp[k] = pack2(disv*q2[k].x, disv*q2[k].y);
      pp[k] = pack2(dinvv*p2[k].x, dinvv*p2[k].y);
      gp[k] = pack2(fmaf(e1, x0, p2[k].x), fmaf(e1, x1, p2[k].y));
      rp[k] = pack2(zinv*r2[k].x, zinv*r2[k].y);
    }
    *(uint4*)(Qb + o) = qo;
    *(uint4*)(Pm + o) = po;
    *(uint4*)(Gb + o) = go;
    *(uint4*)(Rb + o) = ro;
    if (t == 0) b0[wv] = disv*qd;
  }
}

// ---------------- MFMA helpers, M=64 tile ----------------
__device__ __forceinline__ void stageB_async(u16* lds, const u16* __restrict__ w, int tid){
  int lane = tid & 63, wave = tid >> 6;
  #pragma unroll
  for (int i = 0; i < 8; i++){
    int cb = wave*64 + 256*i;
    async16(w + (size_t)(cb + lane)*8, lds + (size_t)cb*8);
  }
}
__device__ __forceinline__ void stageA64_async(u16* lds, const u16* __restrict__ src,
                                               int mbase, int Nn, int tid){
  int lane = tid & 63, wave = tid >> 6;
  #pragma unroll
  for (int i = 0; i < 4; i++){
    int cb = wave*64 + 256*i;
    int gr = mbase + ((cb + lane) >> 4);
    if (gr < Nn)
      async16(src + ((size_t)mbase*16 + cb + lane)*8, lds + (size_t)cb*8);
  }
}
__device__ __forceinline__ void stageA64_f32(u16* lds, const float* __restrict__ src,
                                             int mbase, int Nn, int tid){
  #pragma unroll
  for (int i = 0; i < 4; i++){
    int chunk = tid + 256*i;
    int r = chunk >> 4;
    int c = chunk & 15;
    uint4 v = {0u,0u,0u,0u};
    int gr = mbase + r;
    if (gr < Nn) v = cvt8(src + (size_t)gr*HD + c*8);
    *(uint4*)(lds + (r*16 + (c ^ (r & 15)))*8) = v;
  }
}
__device__ __forceinline__ void mfma_tile64(const u16* Als, const u16* Bls,
                                            int m0, int lane, f32x4 acc[8]){
  int quad = lane >> 4, lr = lane & 15;
  #pragma unroll
  for (int ks = 0; ks < 4; ks++){
    int q = ks*4 + quad;
    short8 a, b[8];
    int row = m0 + lr;
    a = *(const short8*)(Als + (row*16 + (q ^ lr))*8);
    #pragma unroll
    for (int ct = 0; ct < 8; ct++){
      int brow = ct*16 + lr;
      b[ct] = *(const short8*)(Bls + (brow*16 + (q ^ lr))*8);
    }
    #pragma unroll
    for (int ct = 0; ct < 8; ct++)
      acc[ct] = __builtin_amdgcn_mfma_f32_16x16x32_bf16(a, b[ct], acc[ct], 0, 0, 0);
  }
}

// ---------------- lin1: xh(bf16,swz) = f32(x) @ W^T + b ----------------
__global__ __launch_bounds__(256,3)
void k_gemm1(const float* __restrict__ A, const u16* __restrict__ Wb, const float* __restrict__ bias,
             const float* __restrict__ sm, float4* __restrict__ nd, u32* __restrict__ maxs,
             int Nn, u16* __restrict__ out)
{
  __shared__ __align__(16) u16 Als[64*128];
  __shared__ __align__(16) u16 Bls[128*128];
  __shared__ float mred[4];
  int tid = threadIdx.x;
  int lane = tid & 63, wave = tid >> 6;
  int m0 = wave*16, mbase = blockIdx.x*64;
  int quad = lane >> 4, lr = lane & 15;
  f32x4 acc[8];
  #pragma unroll
  for (int ct=0;ct<8;ct++) acc[ct] = (f32x4){0.f,0.f,0.f,0.f};
  stageB_async(Bls, Wb, tid);
  stageA64_f32(Als, A, mbase, Nn, tid);
  __syncthreads();
  mfma_tile64(Als, Bls, m0, lane, acc);
  #pragma unroll
  for (int ct=0;ct<8;ct++){
    float bc = bias[ct*16+lr];
    #pragma unroll
    for (int r=0;r<4;r++) acc[ct][r] = sane(acc[ct][r] + bc);
  }
  // store swizzled
  #pragma unroll
  for (int ct=0;ct<8;ct++){
    int c2 = ct*2 + (lr >> 3);
    #pragma unroll
    for (int r=0;r<4;r++){
      int grow = mbase + m0 + quad*4 + r;
      if (grow < Nn) out[(size_t)grow*HD + (c2 ^ (grow & 15))*8 + (lr & 7)] = f2b(acc[ct][r]);
    }
  }
  // epilogue: s,d for layer 0 + global maxS
  {
    const float* wsv = sm + 32;
    const float* wdv = sm + 416;
    float sp[4] = {0.f,0.f,0.f,0.f}, dp[4] = {0.f,0.f,0.f,0.f};
    #pragma unroll
    for (int ct=0;ct<8;ct++){
      float wsc = wsv[ct*16+lr], wdc = wdv[ct*16+lr];
      #pragma unroll
      for (int r=0;r<4;r++){
        sp[r] = fmaf(acc[ct][r], wsc, sp[r]);
        dp[r] = fmaf(acc[ct][r], wdc, dp[r]);
      }
    }
    #pragma unroll
    for (int off=1; off<16; off<<=1)
      #pragma unroll
      for (int r=0;r<4;r++){ sp[r] += __shfl_xor(sp[r], off); dp[r] += __shfl_xor(dp[r], off); }
    float ms = -3.4e38f;
    #pragma unroll
    for (int r=0;r<4;r++){
      int grow = mbase + m0 + quad*4 + r;
      if (grow < Nn){
        ms = fmaxf(ms, sp[r]);
        if (lr == 0) *(float2*)&nd[grow] = make_float2(sp[r], dp[r]);
      }
    }
    ms = fmaxf(ms, __shfl_xor(ms, 16));
    ms = fmaxf(ms, __shfl_xor(ms, 32));
    if (lane == 0) mred[wave] = ms;
    __syncthreads();
    if (tid == 0){
      float m = fmaxf(fmaxf(mred[0],mred[1]), fmaxf(mred[2],mred[3]));
      atomicMax(maxs + 0, fenc(m));
    }
  }
}

// ---------------- fused layer: 5 all-async GEMMs + elu mix + s/d epilogue ---
__global__ __launch_bounds__(256,3)
void k_layer3(const u16* __restrict__ X, const u16* __restrict__ Qb,
              const u16* __restrict__ Pm, const u16* __restrict__ Gb, const u16* __restrict__ Rb,
              float4* __restrict__ nd, const float* __restrict__ b0,
              const u16* __restrict__ wsb,
              const float* __restrict__ gcnB, const float* __restrict__ ginB,
              const float* __restrict__ sm, u32* __restrict__ maxs,
              int layer, int Nn, u16* __restrict__ out)
{
  __shared__ __align__(16) u16 At[64*128];
  __shared__ __align__(16) u16 Bt[128*128];
  __shared__ float mred[4];
  int tid = threadIdx.x;
  int lane = tid & 63, wave = tid >> 6;
  int m0 = wave*16, mbase = blockIdx.x*64;
  int quad = lane >> 4, lr = lane & 15;
  float w0 = sm[layer*4+0], w1 = sm[layer*4+1], w2 = sm[layer*4+2], w3 = sm[layer*4+3];
  const u16* gcnWb = wsb + (size_t)(1  + layer)*16384;
  const u16* WsWb  = wsb + (size_t)(4  + layer)*16384;
  const u16* WnWb  = wsb + (size_t)(7  + layer)*16384;
  const u16* ginWb = wsb + (size_t)(10 + layer)*16384;
  const u16* gatWb = wsb + (size_t)(13 + layer)*16384;

  f32x4 mix[8];
  f32x4 acc[8];
  float b0r[4];
  #pragma unroll
  for (int r=0;r<4;r++){
    int grow = mbase + m0 + quad*4 + r;
    b0r[r] = (grow < Nn) ? b0[grow] : 0.f;
  }

  // ---- op0: GCN ----
  stageB_async(Bt, gcnWb, tid);
  stageA64_async(At, Qb, mbase, Nn, tid);
  __syncthreads();
  #pragma unroll
  for (int ct=0;ct<8;ct++) acc[ct] = (f32x4){0.f,0.f,0.f,0.f};
  mfma_tile64(At, Bt, m0, lane, acc);
  {
    float gb[8];
    #pragma unroll
    for (int ct=0;ct<8;ct++) gb[ct] = gcnB[layer*HD + ct*16+lr];
    #pragma unroll
    for (int ct=0;ct<8;ct++)
      #pragma unroll
      for (int r=0;r<4;r++)
        mix[ct][r] = w0 * eluf(acc[ct][r] + b0r[r]*gb[ct]);
  }
  __syncthreads();

  // ---- op1: SAGE self (X swizzled async) ----
  stageB_async(Bt, WsWb, tid);
  stageA64_async(At, X, mbase, Nn, tid);
  __syncthreads();
  #pragma unroll
  for (int ct=0;ct<8;ct++) acc[ct] = (f32x4){0.f,0.f,0.f,0.f};
  mfma_tile64(At, Bt, m0, lane, acc);
  __syncthreads();
  // ---- SAGE neighbor (Pm pre-scaled, async) ----
  stageB_async(Bt, WnWb, tid);
  stageA64_async(At, Pm, mbase, Nn, tid);
  __syncthreads();
  mfma_tile64(At, Bt, m0, lane, acc);
  #pragma unroll
  for (int ct=0;ct<8;ct++)
    #pragma unroll
    for (int r=0;r<4;r++)
      mix[ct][r] += w1 * eluf(acc[ct][r]);
  __syncthreads();

  // ---- op2: GIN (Gb pre-built, async) ----
  stageB_async(Bt, ginWb, tid);
  stageA64_async(At, Gb, mbase, Nn, tid);
  __syncthreads();
  #pragma unroll
  for (int ct=0;ct<8;ct++) acc[ct] = (f32x4){0.f,0.f,0.f,0.f};
  mfma_tile64(At, Bt, m0, lane, acc);
  {
    float gib[8];
    #pragma unroll
    for (int ct=0;ct<8;ct++) gib[ct] = ginB[layer*HD + ct*16+lr];
    #pragma unroll
    for (int ct=0;ct<8;ct++)
      #pragma unroll
      for (int r=0;r<4;r++)
        mix[ct][r] += w2 * eluf(acc[ct][r] + gib[ct]);
  }
  __syncthreads();

  // ---- op3: GAT (Rb async) ----
  stageB_async(Bt, gatWb, tid);
  stageA64_async(At, Rb, mbase, Nn, tid);
  __syncthreads();
  #pragma unroll
  for (int ct=0;ct<8;ct++) acc[ct] = (f32x4){0.f,0.f,0.f,0.f};
  mfma_tile64(At, Bt, m0, lane, acc);
  #pragma unroll
  for (int ct=0;ct<8;ct++)
    #pragma unroll
    for (int r=0;r<4;r++)
      mix[ct][r] = sane(mix[ct][r] + w3 * eluf(acc[ct][r]));

  // ---- store swizzled ----
  #pragma unroll
  for (int ct=0;ct<8;ct++){
    int c2 = ct*2 + (lr >> 3);
    #pragma unroll
    for (int r=0;r<4;r++){
      int grow = mbase + m0 + quad*4 + r;
      if (grow < Nn) out[(size_t)grow*HD + (c2 ^ (grow & 15))*8 + (lr & 7)] = f2b(mix[ct][r]);
    }
  }
  // ---- epilogue: s,d for next layer + global maxS ----
  if (layer < 2){
    const float* wsv = sm + 32  + (layer+1)*128;
    const float* wdv = sm + 416 + (layer+1)*128;
    float sp[4] = {0.f,0.f,0.f,0.f}, dp[4] = {0.f,0.f,0.f,0.f};
    #pragma unroll
    for (int ct=0;ct<8;ct++){
      float wsc = wsv[ct*16+lr], wdc = wdv[ct*16+lr];
      #pragma unroll
      for (int r=0;r<4;r++){
        sp[r] = fmaf(mix[ct][r], wsc, sp[r]);
        dp[r] = fmaf(mix[ct][r], wdc, dp[r]);
      }
    }
    #pragma unroll
    for (int off=1; off<16; off<<=1)
      #pragma unroll
      for (int r=0;r<4;r++){ sp[r] += __shfl_xor(sp[r], off); dp[r] += __shfl_xor(dp[r], off); }
    float ms = -3.4e38f;
    #pragma unroll
    for (int r=0;r<4;r++){
      int grow = mbase + m0 + quad*4 + r;
      if (grow < Nn){
        ms = fmaxf(ms, sp[r]);
        if (lr == 0) *(float2*)&nd[grow] = make_float2(sp[r], dp[r]);
      }
    }
    ms = fmaxf(ms, __shfl_xor(ms, 16));
    ms = fmaxf(ms, __shfl_xor(ms, 32));
    if (lane == 0) mred[wave] = ms;
    __syncthreads();
    if (tid == 0){
      float m = fmaxf(fmaxf(mred[0],mred[1]), fmaxf(mred[2],mred[3]));
      atomicMax(maxs + layer + 1, fenc(m));
    }
  }
}

// ------- classifier with fused skip/layer-agg (inputs swizzled) ----------
__global__ __launch_bounds__(256)
void k_nc(const u16* __restrict__ X1, const u16* __restrict__ X2, const u16* __restrict__ X3,
          const float* __restrict__ W, const float* __restrict__ bias,
          const float* __restrict__ sm, int Nn, float* __restrict__ out)
{
  __shared__ __align__(16) u16 xs[32*136];
  __shared__ __align__(16) float wn[40*132];
  __shared__ float bs[40];
  int t = threadIdx.x;
  int nb = blockIdx.x*32;
  float c1 = sm[12], c2 = sm[13], la0 = sm[14], la1 = sm[15], la2 = sm[16];
  #pragma unroll
  for (int i = 0; i < 2; i++){
    int chunk = t + 256*i;
    int r = chunk >> 4, c = chunk & 15;
    uint4 v = {0u,0u,0u,0u};
    int gr = nb + r;
    if (gr < Nn){
      size_t o = (size_t)gr*HD + ((c ^ (gr & 15))*8);
      uint4 u1 = *(const uint4*)(X1 + o);
      uint4 u2 = *(const uint4*)(X2 + o);
      uint4 u3 = *(const uint4*)(X3 + o);
      u32* u1p = (u32*)&u1; u32* u2p = (u32*)&u2; u32* u3p = (u32*)&u3; u32* vp = (u32*)&v;
      #pragma unroll
      for (int k = 0; k < 4; k++){
        float o0, o1;
        {
          float a1 = lo2f(u1p[k]), a2 = lo2f(u2p[k]), a3 = lo2f(u3p[k]);
          float t0 = a3, t1 = c1*a1, t2 = c2*a2;
          float smm = t0 + t1 + t2;
          float mx = fmaxf(fmaxf(t0,t1),t2);
          o0 = la0*reluf(mx) + la1*reluf(smm*(1.f/3.f)) + la2*reluf(smm);
        }
        {
          float a1 = hi2f(u1p[k]), a2 = hi2f(u2p[k]), a3 = hi2f(u3p[k]);
          float t0 = a3, t1 = c1*a1, t2 = c2*a2;
          float smm = t0 + t1 + t2;
          float mx = fmaxf(fmaxf(t0,t1),t2);
          o1 = la0*reluf(mx) + la1*reluf(smm*(1.f/3.f)) + la2*reluf(smm);
        }
        vp[k] = pack2(sane(o0), sane(o1));
      }
    }
    *(uint4*)(xs + r*136 + c*8) = v;
  }
  #pragma unroll
  for (int i = 0; i < 5; i++){
    int chunk = t + 256*i;
    int r = chunk >> 5, c = chunk & 31;
    *(float4*)(wn + r*132 + c*4) = *(const float4*)(W + r*HD + c*4);
  }
  if (t < 40) bs[t] = bias[t];
  __syncthreads();
  int nl = t >> 3, cg = t & 7;
  float acc[5];
  #pragma unroll
  for (int j = 0; j < 5; j++) acc[j] = bs[cg + 8*j];
  for (int k = 0; k < 128; k++){
    float xv = b2f(xs[nl*136 + k]);
    #pragma unroll
    for (int j = 0; j < 5; j++)
      acc[j] = fmaf(xv, wn[(cg + 8*j)*132 + k], acc[j]);
  }
  int gr = nb + nl;
  if (gr < Nn){
    #pragma unroll
    for (int j = 0; j < 5; j++)
      out[(size_t)gr*40 + cg + 8*j] = sane(acc[j]);
  }
}

// ---------------- host ----------------
extern "C" void kernel_launch(void* const* d_in, const int* in_sizes, int n_in,
                              void* d_out, int out_size, void* d_ws, size_t ws_size,
                              hipStream_t stream)
{
  (void)n_in; (void)out_size; (void)ws_size;
  const int N = in_sizes[0] / HD;
  const int E = in_sizes[1] / 2;
  const float* x      = (const float*)d_in[0];
  const int*   ei     = (const int*)d_in[1];
  const float* na_a   = (const float*)d_in[2];
  const float* sc_a   = (const float*)d_in[3];
  const float* la_a   = (const float*)d_in[4];
  const float* lin1W  = (const float*)d_in[5];
  const float* lin1b  = (const float*)d_in[6];
  const float* gcnW   = (const float*)d_in[7];
  const float* gcnB   = (const float*)d_in[8];
  const float* sageWs = (const float*)d_in[9];
  const float* sageWn = (const float*)d_in[10];
  const float* ginW   = (const float*)d_in[11];
  const float* ginB   = (const float*)d_in[12];
  const float* ginE   = (const float*)d_in[13];
  const float* gatW   = (const float*)d_in[14];
  const float* gatAs  = (const float*)d_in[15];
  const float* gatAd  = (const float*)d_in[16];
  const float* ncW    = (const float*)d_in[17];
  const float* ncB    = (const float*)d_in[18];

  char* base = (char*)d_ws;
  size_t off = 0;
  auto alloc = [&](size_t b) -> void* {
    void* p = base + off;
    off += (b + 255) & ~(size_t)255;
    return p;
  };
  const int NB = (N + 1023) / 1024;
  float*  smalls = (float*)alloc(4096);
  u32*    maxs   = (u32*)alloc(256);
  int*    cnt    = (int*)alloc((size_t)N*4);
  int*    rowptr = (int*)alloc(((size_t)N+1)*4);
  int*    cursor = (int*)alloc((size_t)N*4);
  int*    bsum   = (int*)alloc(4096);
  int*    boffs  = (int*)alloc(4096);
  float4* nd     = (float4*)alloc((size_t)N*16);   // (s, d, dis, dinv)
  float*  b0     = (float*)alloc((size_t)N*4);
  int*    csr    = (int*)alloc((size_t)E*4);
  u16*    wsb    = (u16*)alloc((size_t)16*16384*2);
  u16*    xh     = (u16*)alloc((size_t)N*HD*2);   // swizzled; reused as x3
  u16*    x1     = (u16*)alloc((size_t)N*HD*2);
  u16*    x2     = (u16*)alloc((size_t)N*HD*2);
  u16*    Qb     = (u16*)alloc((size_t)N*HD*2);
  u16*    Pm     = (u16*)alloc((size_t)N*HD*2);
  u16*    Gb     = (u16*)alloc((size_t)N*HD*2);
  u16*    Rb     = (u16*)alloc((size_t)N*HD*2);

  hipMemsetAsync(cnt, 0, (size_t)N*4, stream);
  k_small<<<1,128,0,stream>>>(na_a, sc_a, la_a, gatW, gatAs, gatAd, ginE, smalls, maxs);
  k_wcvt<<<128,256,0,stream>>>(lin1W, gcnW, sageWs, sageWn, ginW, gatW, wsb);
  int ebl = (E + 255)/256;
  k_count<<<ebl,256,0,stream>>>(ei, E, cnt);
  k_scan1<<<NB,256,0,stream>>>(cnt, N, bsum);
  k_scan2<<<1,1024,0,stream>>>(bsum, NB, boffs, rowptr, N);
  k_scan3<<<NB,256,0,stream>>>(cnt, boffs, N, rowptr, cursor, nd);
  k_fill<<<ebl,256,0,stream>>>(ei, E, cursor, csr);
  int gbl64 = (N + 63)/64;
  k_gemm1<<<gbl64,256,0,stream>>>(x, wsb, lin1b, smalls, nd, maxs, N, xh);
  const u16* xc = xh;
  u16* outs[3] = {x1, x2, xh};    // x3 reuses xh (dead after layer 0)
  int wbl = (N + 3)/4;
  for (int l = 0; l < 3; l++){
    k_agg<<<wbl,256,0,stream>>>(xc, rowptr, csr, nd, smalls, maxs, l, N, Qb, Pm, Gb, Rb, b0);
    k_layer3<<<gbl64,256,0,stream>>>(xc, Qb, Pm, Gb, Rb, nd, b0, wsb,
                                     gcnB, ginB, smalls, maxs, l, N, outs[l]);
    xc = outs[l];
  }
  int ncbl = (N + 31)/32;
  k_nc<<<ncbl,256,0,stream>>>(x1, x2, xh, ncW, ncB, smalls, N, (float*)d_out);
}